// Round 3
// baseline (1785.951 us; speedup 1.0000x reference)
//
#include <hip/hip_runtime.h>
#include <hip/hip_bf16.h>
#include <math.h>

// ---- problem constants ----
#define NB    4          // batch
#define LSEQ  8192       // H*W
#define HH    64
#define WW    128
#define DMODEL 256
#define DINNER 512
#define NH    8          // heads
#define DSTATE 64
#define DPROJ 1160       // 2*512 + 2*64 + 8
#define CONVD 640        // 512 + 128
#define MROWS (NB*LSEQ)  // 32768

typedef unsigned short bf16_t;
typedef __attribute__((ext_vector_type(8))) unsigned short ushort8v;

static __device__ __forceinline__ float bf2f(bf16_t u) {
    return __uint_as_float(((unsigned)u) << 16);
}
static __device__ __forceinline__ bf16_t f2bf(float f) {
    unsigned u = __float_as_uint(f);
    u += 0x7FFFu + ((u >> 16) & 1u);   // round-nearest-even
    return (bf16_t)(u >> 16);
}

// =====================================================================
// Tiled GEMM:  C[M,N] = A[M,K] @ B[N,K]^T   (row-major)
// A: f32 or bf16-bits; B: f32 weights; C: f32 or bf16-bits.
// 128x128 tile, BK=8, 256 threads, 8x8 per thread, f32 compute.
// =====================================================================
template <typename TA, typename TC>
__global__ __launch_bounds__(256) void gemm_bt(
    const TA* __restrict__ A, const float* __restrict__ B,
    TC* __restrict__ C, int M, int N, int K)
{
    __shared__ float As[8][132];
    __shared__ float Bs[8][132];
    const int tid = threadIdx.x;
    const int m0 = blockIdx.y * 128;
    const int n0 = blockIdx.x * 128;
    const int tx = tid & 15;        // n dir
    const int ty = tid >> 4;        // m dir
    const int la_m = tid >> 1;      // 0..127
    const int la_k = (tid & 1) * 4; // 0 or 4

    float acc[8][8];
    #pragma unroll
    for (int i = 0; i < 8; ++i)
        #pragma unroll
        for (int j = 0; j < 8; ++j) acc[i][j] = 0.f;

    for (int k0 = 0; k0 < K; k0 += 8) {
        float a0, a1, a2, a3;
        const size_t aoff = (size_t)(m0 + la_m) * K + k0 + la_k;
        if constexpr (sizeof(TA) == 2) {
            ushort4 av = *(const ushort4*)&A[aoff];
            a0 = bf2f(av.x); a1 = bf2f(av.y); a2 = bf2f(av.z); a3 = bf2f(av.w);
        } else {
            float4 av = *(const float4*)&A[aoff];
            a0 = av.x; a1 = av.y; a2 = av.z; a3 = av.w;
        }
        As[la_k + 0][la_m] = a0; As[la_k + 1][la_m] = a1;
        As[la_k + 2][la_m] = a2; As[la_k + 3][la_m] = a3;
        const int brow = n0 + la_m;
        float4 bv = make_float4(0.f, 0.f, 0.f, 0.f);
        if (brow < N) bv = *(const float4*)&B[(size_t)brow * K + k0 + la_k];
        Bs[la_k + 0][la_m] = bv.x; Bs[la_k + 1][la_m] = bv.y;
        Bs[la_k + 2][la_m] = bv.z; Bs[la_k + 3][la_m] = bv.w;
        __syncthreads();
        #pragma unroll
        for (int kk = 0; kk < 8; ++kk) {
            float4 x0 = *(const float4*)&As[kk][ty * 8];
            float4 x1 = *(const float4*)&As[kk][ty * 8 + 4];
            float4 y0 = *(const float4*)&Bs[kk][tx * 8];
            float4 y1 = *(const float4*)&Bs[kk][tx * 8 + 4];
            float a[8] = {x0.x, x0.y, x0.z, x0.w, x1.x, x1.y, x1.z, x1.w};
            float b[8] = {y0.x, y0.y, y0.z, y0.w, y1.x, y1.y, y1.z, y1.w};
            #pragma unroll
            for (int i = 0; i < 8; ++i)
                #pragma unroll
                for (int j = 0; j < 8; ++j) acc[i][j] += a[i] * b[j];
        }
        __syncthreads();
    }
    #pragma unroll
    for (int i = 0; i < 8; ++i) {
        const int rowm = m0 + ty * 8 + i;
        #pragma unroll
        for (int j = 0; j < 8; ++j) {
            const int col = n0 + tx * 8 + j;
            if (col < N) {
                if constexpr (sizeof(TC) == 2)
                    C[(size_t)rowm * N + col] = f2bf(acc[i][j]);
                else
                    C[(size_t)rowm * N + col] = acc[i][j];
            }
        }
    }
}

// =====================================================================
__global__ __launch_bounds__(256) void zero_kernel(float* __restrict__ p, int n)
{
    const int i = blockIdx.x * 256 + threadIdx.x;
    if (i < n) p[i] = 0.f;
}

// =====================================================================
// dt = softplus(zx[:,1152+h] + dt_bias[h])
// =====================================================================
__global__ __launch_bounds__(256) void dt_kernel(
    const bf16_t* __restrict__ zx, const float* __restrict__ dt_bias,
    float* __restrict__ dtbuf)
{
    const int idx = blockIdx.x * 256 + threadIdx.x;   // < 32768*8
    const int h = idx & 7;
    const int row = idx >> 3;
    const float v = bf2f(zx[(size_t)row * DPROJ + (DINNER + CONVD) + h]) + dt_bias[h];
    const float sp = (v > 0.f) ? (v + log1pf(expf(-v))) : log1pf(expf(v));
    dtbuf[idx] = sp;
}

// =====================================================================
// 3x3 depthwise conv (SAME, zero pad) + bias + SiLU.
// input: zx channels [512, 512+640), viewed as (b, H, W, 640).
// =====================================================================
__global__ __launch_bounds__(256) void conv_silu_kernel(
    const bf16_t* __restrict__ zx,
    const float* __restrict__ wA, const float* __restrict__ bA,
    const float* __restrict__ wB, const float* __restrict__ bB,
    bf16_t* __restrict__ out)
{
    const int idx = blockIdx.x * 256 + threadIdx.x;   // < 4*8192*640
    const int c = idx % CONVD;
    const int t = idx / CONVD;
    const int l = t & (LSEQ - 1);
    const int b = t >> 13;
    const int hh = l >> 7;
    const int ww = l & (WW - 1);
    const float* wp = (b < 2) ? wA : wB;
    const float* bp = (b < 2) ? bA : bB;
    const float* w9 = wp + c * 9;
    float acc = bp[c];
    #pragma unroll
    for (int ki = -1; ki <= 1; ++ki) {
        const int hi = hh + ki;
        if ((unsigned)hi >= (unsigned)HH) continue;
        #pragma unroll
        for (int kj = -1; kj <= 1; ++kj) {
            const int wi = ww + kj;
            if ((unsigned)wi >= (unsigned)WW) continue;
            const size_t off = ((size_t)(b * LSEQ + hi * WW + wi)) * DPROJ + DINNER + c;
            acc += bf2f(zx[off]) * w9[(ki + 1) * 3 + (kj + 1)];
        }
    }
    out[idx] = f2bf(acc / (1.f + expf(-acc)));  // silu
}

// =====================================================================
// KV[b,h,s,p] += sum_l B[b,l,s] * x[b,l,h,p] * dt[b,l,h]*exp(A_log[h])
// grid (lchunk=16, h=8, b=4), block 256. LDS-tiled 32 rows at a time.
// KV pre-zeroed; chunks combine via atomicAdd.
// =====================================================================
__global__ __launch_bounds__(256) void kv_kernel(
    const bf16_t* __restrict__ xconv, const float* __restrict__ dtbuf,
    const float* __restrict__ A_log, float* __restrict__ KV)
{
    const int h = blockIdx.y, b = blockIdx.z;
    const int l0 = blockIdx.x * 512;
    const int tid = threadIdx.x;
    __shared__ float Bt[32][64];
    __shared__ float Xt[32][64];
    const float eA = expf(A_log[h]);
    const int s  = tid >> 2;         // 0..63
    const int pq = (tid & 3) * 16;   // 0,16,32,48
    const int lr = tid >> 3;         // 0..31
    const int jj = (tid & 7) * 8;    // 0..56
    float acc[16];
    #pragma unroll
    for (int i = 0; i < 16; ++i) acc[i] = 0.f;

    for (int lt = 0; lt < 512; lt += 32) {
        const int row = b * LSEQ + l0 + lt + lr;
        const bf16_t* rp = xconv + (size_t)row * CONVD;
        const float dA = dtbuf[row * NH + h] * eA;
        ushort8v bvec = *(const ushort8v*)(rp + DINNER + jj);
        ushort8v xvec = *(const ushort8v*)(rp + h * 64 + jj);
        #pragma unroll
        for (int q = 0; q < 8; ++q) {
            Bt[lr][jj + q] = bf2f(bvec[q]);
            Xt[lr][jj + q] = bf2f(xvec[q]) * dA;
        }
        __syncthreads();
        #pragma unroll 8
        for (int r = 0; r < 32; ++r) {
            const float bs = Bt[r][s];
            #pragma unroll
            for (int i = 0; i < 16; ++i) acc[i] += bs * Xt[r][pq + i];
        }
        __syncthreads();
    }
    float* kvp = KV + (((size_t)(b * NH + h) * 64) + s) * 64 + pq;
    #pragma unroll
    for (int i = 0; i < 16; ++i) atomicAdd(&kvp[i], acc[i]);
}

// =====================================================================
// y = C·KV + x·D  -> LayerNorm -> *g+b -> *z  -> ybuf (bf16)
// block = 512 threads (one channel each), YROWS rows per block.
// =====================================================================
#define YROWS 16
__global__ __launch_bounds__(512) void yln_kernel(
    const bf16_t* __restrict__ xconv, const float* __restrict__ KV,
    const float* __restrict__ DA, const float* __restrict__ DB,
    const float* __restrict__ ln_g, const float* __restrict__ ln_b,
    const bf16_t* __restrict__ zsrc, bf16_t* __restrict__ ybuf)
{
    const int b = blockIdx.y;
    const int row0 = blockIdx.x * YROWS;
    const int c = threadIdx.x;
    const int h = c >> 6, p = c & 63;
    float kv[64];
    const float* kvp = KV + ((size_t)(b * NH + h) * 64) * 64 + p;
    #pragma unroll
    for (int s = 0; s < 64; ++s) kv[s] = kvp[s * 64];
    const float Dv = (b < 2) ? DA[h] : DB[h];
    const float g = ln_g[c], be = ln_b[c];
    __shared__ float Cl[64];
    __shared__ float red[2][8];

    for (int r = 0; r < YROWS; ++r) {
        const int row = b * LSEQ + row0 + r;
        if (c < 64) Cl[c] = bf2f(xconv[(size_t)row * CONVD + DINNER + DSTATE + c]);
        __syncthreads();
        const float x = bf2f(xconv[(size_t)row * CONVD + c]);
        float y = x * Dv;
        #pragma unroll
        for (int s = 0; s < 64; ++s) y += Cl[s] * kv[s];
        float s1 = y, s2 = y * y;
        #pragma unroll
        for (int off = 32; off > 0; off >>= 1) {
            s1 += __shfl_xor(s1, off, 64);
            s2 += __shfl_xor(s2, off, 64);
        }
        if ((c & 63) == 0) { red[0][c >> 6] = s1; red[1][c >> 6] = s2; }
        __syncthreads();
        float t1 = 0.f, t2 = 0.f;
        #pragma unroll
        for (int w2 = 0; w2 < 8; ++w2) { t1 += red[0][w2]; t2 += red[1][w2]; }
        const float mu = t1 * (1.f / 512.f);
        const float var = t2 * (1.f / 512.f) - mu * mu;
        const float rstd = rsqrtf(var + 1e-5f);
        const float z = bf2f(zsrc[(size_t)row * DPROJ + c]);
        ybuf[(size_t)row * DINNER + c] = f2bf(((y - mu) * rstd * g + be) * z);
        __syncthreads();
    }
}

// =====================================================================
extern "C" void kernel_launch(void* const* d_in, const int* in_sizes, int n_in,
                              void* d_out, int out_size, void* d_ws, size_t ws_size,
                              hipStream_t stream)
{
    const float* u        = (const float*)d_in[0];
    const float* W_in     = (const float*)d_in[3];
    const float* W_st     = (const float*)d_in[4];
    const float* conv_l_w = (const float*)d_in[5];
    const float* conv_l_b = (const float*)d_in[6];
    const float* conv_r_w = (const float*)d_in[7];
    const float* conv_r_b = (const float*)d_in[8];
    const float* conv_w   = (const float*)d_in[9];
    const float* conv_b   = (const float*)d_in[10];
    const float* dt_bias  = (const float*)d_in[11];
    const float* A_log    = (const float*)d_in[12];
    const float* D_l      = (const float*)d_in[13];
    const float* D_r      = (const float*)d_in[14];
    const float* Dp       = (const float*)d_in[15];
    const float* ln_g     = (const float*)d_in[16];
    const float* ln_b     = (const float*)d_in[17];
    const float* W_out    = (const float*)d_in[18];
    float* out = (float*)d_out;

    // ---- workspace layout (bf16 intermediates): 146 MB total ----
    char* ws = (char*)d_ws;
    const size_t ZX_B    = (size_t)MROWS * DPROJ * 2;   //  76,021,760
    const size_t XCONV_B = (size_t)MROWS * CONVD * 2;   //  41,943,040
    const size_t YBUF_B  = (size_t)MROWS * DINNER * 2;  //  33,554,432
    const size_t DT_B    = (size_t)MROWS * NH * 4;      //   1,048,576
    bf16_t* zx    = (bf16_t*)(ws);
    bf16_t* xconv = (bf16_t*)(ws + ZX_B);
    bf16_t* ybuf  = (bf16_t*)(ws + ZX_B + XCONV_B);
    float*  dtbuf = (float*) (ws + ZX_B + XCONV_B + YBUF_B);
    float*  KV    = (float*) (ws + ZX_B + XCONV_B + YBUF_B + DT_B);
    const int KV_N = NB * NH * 64 * 64;                 // 131072 floats

    const dim3 gemmGridP(10, MROWS / 128);   // N=1160
    const dim3 gemmGridO(2,  MROWS / 128);   // N=256
    const dim3 kvGrid(16, NH, NB);
    const dim3 ylnGrid(LSEQ / YROWS, NB);

    // ---------------- pass 1 ----------------
    gemm_bt<float, bf16_t><<<gemmGridP, 256, 0, stream>>>(u, W_in, zx, MROWS, DPROJ, DMODEL);
    dt_kernel<<<(MROWS * NH) / 256, 256, 0, stream>>>(zx, dt_bias, dtbuf);
    conv_silu_kernel<<<(MROWS * CONVD) / 256, 256, 0, stream>>>(
        zx, conv_l_w, conv_l_b, conv_r_w, conv_r_b, xconv);
    zero_kernel<<<(KV_N + 255) / 256, 256, 0, stream>>>(KV, KV_N);
    kv_kernel<<<kvGrid, 256, 0, stream>>>(xconv, dtbuf, A_log, KV);
    yln_kernel<<<ylnGrid, 512, 0, stream>>>(xconv, KV, D_l, D_r, ln_g, ln_b, zx, ybuf);

    // ---------------- pass 2 ----------------
    gemm_bt<bf16_t, bf16_t><<<gemmGridP, 256, 0, stream>>>(ybuf, W_st, zx, MROWS, DPROJ, DINNER);
    dt_kernel<<<(MROWS * NH) / 256, 256, 0, stream>>>(zx, dt_bias, dtbuf);
    conv_silu_kernel<<<(MROWS * CONVD) / 256, 256, 0, stream>>>(
        zx, conv_w, conv_b, conv_w, conv_b, xconv);
    zero_kernel<<<(KV_N + 255) / 256, 256, 0, stream>>>(KV, KV_N);
    kv_kernel<<<kvGrid, 256, 0, stream>>>(xconv, dtbuf, A_log, KV);
    yln_kernel<<<ylnGrid, 512, 0, stream>>>(xconv, KV, Dp, Dp, ln_g, ln_b, zx, ybuf);

    // ---------------- output projection ----------------
    gemm_bt<bf16_t, float><<<gemmGridO, 256, 0, stream>>>(ybuf, W_out, out, MROWS, DMODEL, DINNER);
}

// Round 4
// 1074.683 us; speedup vs baseline: 1.6618x; 1.6618x over previous
//
#include <hip/hip_runtime.h>
#include <hip/hip_bf16.h>
#include <math.h>

// ---- problem constants ----
#define NB    4          // batch
#define LSEQ  8192       // H*W
#define HH    64
#define WW    128
#define DMODEL 256
#define DINNER 512
#define NH    8          // heads
#define DSTATE 64
#define DPROJ 1160       // 2*512 + 2*64 + 8
#define CONVD 640        // 512 + 128
#define MROWS (NB*LSEQ)  // 32768

typedef unsigned short bf16_t;
typedef __attribute__((ext_vector_type(8))) unsigned short ushort8v;
typedef __attribute__((ext_vector_type(8))) short short8v;   // MFMA A/B frag (8 bf16)
typedef __attribute__((ext_vector_type(4))) float f32x4;     // MFMA C/D frag

static __device__ __forceinline__ float bf2f(bf16_t u) {
    return __uint_as_float(((unsigned)u) << 16);
}
static __device__ __forceinline__ bf16_t f2bf(float f) {
    unsigned u = __float_as_uint(f);
    u += 0x7FFFu + ((u >> 16) & 1u);   // round-nearest-even
    return (bf16_t)(u >> 16);
}

// =====================================================================
// MFMA GEMM:  C[M,N] = A[M,K]bf16 @ B[Npad,K]bf16^T
// m97 recipe: 128x128 tile, BK=32, 256 thr = 4 waves (2x2), each wave
// 64x64 = 4x4 frags of mfma_f32_16x16x32_bf16. global_load_lds staging.
// M%128==0, K%32==0, Npad%128==0 (B zero-padded rows), C written with
// bounds check col<N. TC = bf16_t or float.
// =====================================================================
template <typename TC>
__global__ __launch_bounds__(256) void gemm_mfma_bt(
    const bf16_t* __restrict__ A, const bf16_t* __restrict__ B,
    TC* __restrict__ C, int M, int N, int K)
{
    __shared__ __align__(16) bf16_t As[128 * 32];
    __shared__ __align__(16) bf16_t Bs[128 * 32];
    const int tid = threadIdx.x;
    const int m0 = blockIdx.y * 128;
    const int n0 = blockIdx.x * 128;
    const int wid = tid >> 6;
    const int lane = tid & 63;
    const int wr = (wid >> 1) * 64;
    const int wc = (wid & 1) * 64;
    const int fr = lane & 15;         // row/col within 16x16 frag
    const int fk = (lane >> 4) * 8;   // k-offset within 32

    f32x4 acc[4][4];
    #pragma unroll
    for (int i = 0; i < 4; ++i)
        #pragma unroll
        for (int j = 0; j < 4; ++j) acc[i][j] = (f32x4){0.f, 0.f, 0.f, 0.f};

    // staging: 256 lanes x 16B = 4KB/issue; tile 8KB -> 2 issues each of A,B
    const int srow = tid >> 2;          // 0..63
    const int scol = (tid & 3) * 8;     // 0,8,16,24
    const bf16_t* gA = A + (size_t)(m0 + srow) * K + scol;
    const bf16_t* gB = B + (size_t)(n0 + srow) * K + scol;
    bf16_t* lA = As + tid * 8;          // byte offset tid*16
    bf16_t* lB = Bs + tid * 8;

    for (int k0 = 0; k0 < K; k0 += 32) {
        __builtin_amdgcn_global_load_lds(
            (const __attribute__((address_space(1))) void*)(gA + k0),
            (__attribute__((address_space(3))) void*)lA, 16, 0, 0);
        __builtin_amdgcn_global_load_lds(
            (const __attribute__((address_space(1))) void*)(gA + (size_t)64 * K + k0),
            (__attribute__((address_space(3))) void*)(lA + 2048), 16, 0, 0);
        __builtin_amdgcn_global_load_lds(
            (const __attribute__((address_space(1))) void*)(gB + k0),
            (__attribute__((address_space(3))) void*)lB, 16, 0, 0);
        __builtin_amdgcn_global_load_lds(
            (const __attribute__((address_space(1))) void*)(gB + (size_t)64 * K + k0),
            (__attribute__((address_space(3))) void*)(lB + 2048), 16, 0, 0);
        __syncthreads();   // compiler emits vmcnt(0) drain before barrier

        short8v a_frag[4], b_frag[4];
        #pragma unroll
        for (int m = 0; m < 4; ++m)
            a_frag[m] = *(const short8v*)&As[(wr + m * 16 + fr) * 32 + fk];
        #pragma unroll
        for (int n = 0; n < 4; ++n)
            b_frag[n] = *(const short8v*)&Bs[(wc + n * 16 + fr) * 32 + fk];
        #pragma unroll
        for (int m = 0; m < 4; ++m)
            #pragma unroll
            for (int n = 0; n < 4; ++n)
                acc[m][n] = __builtin_amdgcn_mfma_f32_16x16x32_bf16(
                    a_frag[m], b_frag[n], acc[m][n], 0, 0, 0);
        __syncthreads();
    }

    // C/D layout (m89/m91 verified): col = lane&15, row = (lane>>4)*4 + q
    #pragma unroll
    for (int mi = 0; mi < 4; ++mi) {
        #pragma unroll
        for (int ni = 0; ni < 4; ++ni) {
            const int col = n0 + wc + ni * 16 + fr;
            if (col < N) {
                #pragma unroll
                for (int q = 0; q < 4; ++q) {
                    const int row = m0 + wr + mi * 16 + (lane >> 4) * 4 + q;
                    if constexpr (sizeof(TC) == 2)
                        C[(size_t)row * N + col] = f2bf(acc[mi][ni][q]);
                    else
                        C[(size_t)row * N + col] = acc[mi][ni][q];
                }
            }
        }
    }
}

// =====================================================================
// f32 -> bf16 conversion (4 elems/thread; n % 4 == 0)
// =====================================================================
__global__ __launch_bounds__(256) void cvt_bf16_kernel(
    const float* __restrict__ in, bf16_t* __restrict__ out, int n)
{
    const int base = (blockIdx.x * 256 + threadIdx.x) * 4;
    if (base >= n) return;
    float4 v = *(const float4*)&in[base];
    ushort4 o;
    o.x = f2bf(v.x); o.y = f2bf(v.y); o.z = f2bf(v.z); o.w = f2bf(v.w);
    *(ushort4*)&out[base] = o;
}

// =====================================================================
// f32 weight [N][K] -> bf16 zero-padded [Npad][K]
// =====================================================================
__global__ __launch_bounds__(256) void wpad_kernel(
    const float* __restrict__ W, bf16_t* __restrict__ Wp,
    int N, int Npad, int K)
{
    const int i = blockIdx.x * 256 + threadIdx.x;
    if (i >= Npad * K) return;
    const int r = i / K, k = i - r * K;
    Wp[i] = (r < N) ? f2bf(W[(size_t)r * K + k]) : (bf16_t)0;
}

// =====================================================================
__global__ __launch_bounds__(256) void zero_kernel(float* __restrict__ p, int n)
{
    const int i = blockIdx.x * 256 + threadIdx.x;
    if (i < n) p[i] = 0.f;
}

// =====================================================================
// dt = softplus(zx[:,1152+h] + dt_bias[h])
// =====================================================================
__global__ __launch_bounds__(256) void dt_kernel(
    const bf16_t* __restrict__ zx, const float* __restrict__ dt_bias,
    float* __restrict__ dtbuf)
{
    const int idx = blockIdx.x * 256 + threadIdx.x;   // < 32768*8
    const int h = idx & 7;
    const int row = idx >> 3;
    const float v = bf2f(zx[(size_t)row * DPROJ + (DINNER + CONVD) + h]) + dt_bias[h];
    const float sp = (v > 0.f) ? (v + log1pf(expf(-v))) : log1pf(expf(v));
    dtbuf[idx] = sp;
}

// =====================================================================
// 3x3 depthwise conv (SAME, zero pad) + bias + SiLU.
// =====================================================================
__global__ __launch_bounds__(256) void conv_silu_kernel(
    const bf16_t* __restrict__ zx,
    const float* __restrict__ wA, const float* __restrict__ bA,
    const float* __restrict__ wB, const float* __restrict__ bB,
    bf16_t* __restrict__ out)
{
    const int idx = blockIdx.x * 256 + threadIdx.x;   // < 4*8192*640
    const int c = idx % CONVD;
    const int t = idx / CONVD;
    const int l = t & (LSEQ - 1);
    const int b = t >> 13;
    const int hh = l >> 7;
    const int ww = l & (WW - 1);
    const float* wp = (b < 2) ? wA : wB;
    const float* bp = (b < 2) ? bA : bB;
    const float* w9 = wp + c * 9;
    float acc = bp[c];
    #pragma unroll
    for (int ki = -1; ki <= 1; ++ki) {
        const int hi = hh + ki;
        if ((unsigned)hi >= (unsigned)HH) continue;
        #pragma unroll
        for (int kj = -1; kj <= 1; ++kj) {
            const int wi = ww + kj;
            if ((unsigned)wi >= (unsigned)WW) continue;
            const size_t off = ((size_t)(b * LSEQ + hi * WW + wi)) * DPROJ + DINNER + c;
            acc += bf2f(zx[off]) * w9[(ki + 1) * 3 + (kj + 1)];
        }
    }
    out[idx] = f2bf(acc / (1.f + expf(-acc)));  // silu
}

// =====================================================================
// KV[b,h,s,p] += sum_l B[b,l,s] * x[b,l,h,p] * dt[b,l,h]*exp(A_log[h])
// =====================================================================
__global__ __launch_bounds__(256) void kv_kernel(
    const bf16_t* __restrict__ xconv, const float* __restrict__ dtbuf,
    const float* __restrict__ A_log, float* __restrict__ KV)
{
    const int h = blockIdx.y, b = blockIdx.z;
    const int l0 = blockIdx.x * 512;
    const int tid = threadIdx.x;
    __shared__ float Bt[32][64];
    __shared__ float Xt[32][64];
    const float eA = expf(A_log[h]);
    const int s  = tid >> 2;         // 0..63
    const int pq = (tid & 3) * 16;   // 0,16,32,48
    const int lr = tid >> 3;         // 0..31
    const int jj = (tid & 7) * 8;    // 0..56
    float acc[16];
    #pragma unroll
    for (int i = 0; i < 16; ++i) acc[i] = 0.f;

    for (int lt = 0; lt < 512; lt += 32) {
        const int row = b * LSEQ + l0 + lt + lr;
        const bf16_t* rp = xconv + (size_t)row * CONVD;
        const float dA = dtbuf[row * NH + h] * eA;
        ushort8v bvec = *(const ushort8v*)(rp + DINNER + jj);
        ushort8v xvec = *(const ushort8v*)(rp + h * 64 + jj);
        #pragma unroll
        for (int q = 0; q < 8; ++q) {
            Bt[lr][jj + q] = bf2f(bvec[q]);
            Xt[lr][jj + q] = bf2f(xvec[q]) * dA;
        }
        __syncthreads();
        #pragma unroll 8
        for (int r = 0; r < 32; ++r) {
            const float bs = Bt[r][s];
            #pragma unroll
            for (int i = 0; i < 16; ++i) acc[i] += bs * Xt[r][pq + i];
        }
        __syncthreads();
    }
    float* kvp = KV + (((size_t)(b * NH + h) * 64) + s) * 64 + pq;
    #pragma unroll
    for (int i = 0; i < 16; ++i) atomicAdd(&kvp[i], acc[i]);
}

// =====================================================================
// y = C·KV + x·D -> LayerNorm -> *g+b -> *z -> ybuf (bf16)
// =====================================================================
#define YROWS 16
__global__ __launch_bounds__(512) void yln_kernel(
    const bf16_t* __restrict__ xconv, const float* __restrict__ KV,
    const float* __restrict__ DA, const float* __restrict__ DB,
    const float* __restrict__ ln_g, const float* __restrict__ ln_b,
    const bf16_t* __restrict__ zsrc, bf16_t* __restrict__ ybuf)
{
    const int b = blockIdx.y;
    const int row0 = blockIdx.x * YROWS;
    const int c = threadIdx.x;
    const int h = c >> 6, p = c & 63;
    float kv[64];
    const float* kvp = KV + ((size_t)(b * NH + h) * 64) * 64 + p;
    #pragma unroll
    for (int s = 0; s < 64; ++s) kv[s] = kvp[s * 64];
    const float Dv = (b < 2) ? DA[h] : DB[h];
    const float g = ln_g[c], be = ln_b[c];
    __shared__ float Cl[64];
    __shared__ float red[2][8];

    for (int r = 0; r < YROWS; ++r) {
        const int row = b * LSEQ + row0 + r;
        if (c < 64) Cl[c] = bf2f(xconv[(size_t)row * CONVD + DINNER + DSTATE + c]);
        __syncthreads();
        const float x = bf2f(xconv[(size_t)row * CONVD + c]);
        float y = x * Dv;
        #pragma unroll
        for (int s = 0; s < 64; ++s) y += Cl[s] * kv[s];
        float s1 = y, s2 = y * y;
        #pragma unroll
        for (int off = 32; off > 0; off >>= 1) {
            s1 += __shfl_xor(s1, off, 64);
            s2 += __shfl_xor(s2, off, 64);
        }
        if ((c & 63) == 0) { red[0][c >> 6] = s1; red[1][c >> 6] = s2; }
        __syncthreads();
        float t1 = 0.f, t2 = 0.f;
        #pragma unroll
        for (int w2 = 0; w2 < 8; ++w2) { t1 += red[0][w2]; t2 += red[1][w2]; }
        const float mu = t1 * (1.f / 512.f);
        const float var = t2 * (1.f / 512.f) - mu * mu;
        const float rstd = rsqrtf(var + 1e-5f);
        const float z = bf2f(zsrc[(size_t)row * DPROJ + c]);
        ybuf[(size_t)row * DINNER + c] = f2bf(((y - mu) * rstd * g + be) * z);
        __syncthreads();
    }
}

// =====================================================================
extern "C" void kernel_launch(void* const* d_in, const int* in_sizes, int n_in,
                              void* d_out, int out_size, void* d_ws, size_t ws_size,
                              hipStream_t stream)
{
    const float* u        = (const float*)d_in[0];
    const float* W_in     = (const float*)d_in[3];
    const float* W_st     = (const float*)d_in[4];
    const float* conv_l_w = (const float*)d_in[5];
    const float* conv_l_b = (const float*)d_in[6];
    const float* conv_r_w = (const float*)d_in[7];
    const float* conv_r_b = (const float*)d_in[8];
    const float* conv_w   = (const float*)d_in[9];
    const float* conv_b   = (const float*)d_in[10];
    const float* dt_bias  = (const float*)d_in[11];
    const float* A_log    = (const float*)d_in[12];
    const float* D_l      = (const float*)d_in[13];
    const float* D_r      = (const float*)d_in[14];
    const float* Dp       = (const float*)d_in[15];
    const float* ln_g     = (const float*)d_in[16];
    const float* ln_b     = (const float*)d_in[17];
    const float* W_out    = (const float*)d_in[18];
    float* out = (float*)d_out;

    // ---- workspace layout: ~172 MB ----
    char* ws = (char*)d_ws;
    const size_t ZX_B    = (size_t)MROWS * DPROJ * 2;   //  76,021,760
    const size_t XCONV_B = (size_t)MROWS * CONVD * 2;   //  41,943,040
    const size_t YBUF_B  = (size_t)MROWS * DINNER * 2;  //  33,554,432
    const size_t DT_B    = (size_t)MROWS * NH * 4;      //   1,048,576
    const size_t KV_B    = (size_t)NB * NH * 64 * 64 * 4; //   524,288
    const size_t UBF_B   = (size_t)MROWS * DMODEL * 2;  //  16,777,216
    const size_t WIN_B   = (size_t)1280 * DMODEL * 2;   //     655,360
    const size_t WST_B   = (size_t)1280 * DINNER * 2;   //   1,310,720
    bf16_t* zx    = (bf16_t*)(ws);
    bf16_t* xconv = (bf16_t*)(ws + ZX_B);
    bf16_t* ybuf  = (bf16_t*)(ws + ZX_B + XCONV_B);
    float*  dtbuf = (float*) (ws + ZX_B + XCONV_B + YBUF_B);
    float*  KV    = (float*) (ws + ZX_B + XCONV_B + YBUF_B + DT_B);
    bf16_t* ubf   = (bf16_t*)(ws + ZX_B + XCONV_B + YBUF_B + DT_B + KV_B);
    bf16_t* WinP  = (bf16_t*)(ws + ZX_B + XCONV_B + YBUF_B + DT_B + KV_B + UBF_B);
    bf16_t* WstP  = (bf16_t*)(ws + ZX_B + XCONV_B + YBUF_B + DT_B + KV_B + UBF_B + WIN_B);
    bf16_t* WoutP = (bf16_t*)(ws + ZX_B + XCONV_B + YBUF_B + DT_B + KV_B + UBF_B + WIN_B + WST_B);
    const int KV_N = NB * NH * 64 * 64;                 // 131072 floats

    const dim3 gemmGridP(10, MROWS / 128);   // Npad=1280
    const dim3 gemmGridO(2,  MROWS / 128);   // N=256
    const dim3 kvGrid(16, NH, NB);
    const dim3 ylnGrid(LSEQ / YROWS, NB);

    // ---- one-time conversions ----
    cvt_bf16_kernel<<<(MROWS * DMODEL / 4 + 255) / 256, 256, 0, stream>>>(u, ubf, MROWS * DMODEL);
    wpad_kernel<<<(1280 * DMODEL + 255) / 256, 256, 0, stream>>>(W_in, WinP, DPROJ, 1280, DMODEL);
    wpad_kernel<<<(1280 * DINNER + 255) / 256, 256, 0, stream>>>(W_st, WstP, DPROJ, 1280, DINNER);
    wpad_kernel<<<(256 * DINNER + 255) / 256, 256, 0, stream>>>(W_out, WoutP, DMODEL, 256, DINNER);

    // ---------------- pass 1 ----------------
    gemm_mfma_bt<bf16_t><<<gemmGridP, 256, 0, stream>>>(ubf, WinP, zx, MROWS, DPROJ, DMODEL);
    dt_kernel<<<(MROWS * NH) / 256, 256, 0, stream>>>(zx, dt_bias, dtbuf);
    conv_silu_kernel<<<(MROWS * CONVD) / 256, 256, 0, stream>>>(
        zx, conv_l_w, conv_l_b, conv_r_w, conv_r_b, xconv);
    zero_kernel<<<(KV_N + 255) / 256, 256, 0, stream>>>(KV, KV_N);
    kv_kernel<<<kvGrid, 256, 0, stream>>>(xconv, dtbuf, A_log, KV);
    yln_kernel<<<ylnGrid, 512, 0, stream>>>(xconv, KV, D_l, D_r, ln_g, ln_b, zx, ybuf);

    // ---------------- pass 2 ----------------
    gemm_mfma_bt<bf16_t><<<gemmGridP, 256, 0, stream>>>(ybuf, WstP, zx, MROWS, DPROJ, DINNER);
    dt_kernel<<<(MROWS * NH) / 256, 256, 0, stream>>>(zx, dt_bias, dtbuf);
    conv_silu_kernel<<<(MROWS * CONVD) / 256, 256, 0, stream>>>(
        zx, conv_w, conv_b, conv_w, conv_b, xconv);
    zero_kernel<<<(KV_N + 255) / 256, 256, 0, stream>>>(KV, KV_N);
    kv_kernel<<<kvGrid, 256, 0, stream>>>(xconv, dtbuf, A_log, KV);
    yln_kernel<<<ylnGrid, 512, 0, stream>>>(xconv, KV, Dp, Dp, ln_g, ln_b, zx, ybuf);

    // ---------------- output projection ----------------
    gemm_mfma_bt<float><<<gemmGridO, 256, 0, stream>>>(ybuf, WoutP, out, MROWS, DMODEL, DINNER);
}

// Round 5
// 787.821 us; speedup vs baseline: 2.2670x; 1.3641x over previous
//
#include <hip/hip_runtime.h>
#include <hip/hip_bf16.h>
#include <math.h>

// ---- problem constants ----
#define NB    4          // batch
#define LSEQ  8192       // H*W
#define HH    64
#define WW    128
#define DMODEL 256
#define DINNER 512
#define NH    8          // heads
#define DSTATE 64
#define DPROJ 1160       // 2*512 + 2*64 + 8
#define CONVD 640        // 512 + 128
#define MROWS (NB*LSEQ)  // 32768
#define KVCH  32         // l-chunks per (b,h) in kv_part

typedef unsigned short bf16_t;
typedef __attribute__((ext_vector_type(8))) unsigned short ushort8v;
typedef __attribute__((ext_vector_type(8))) short short8v;   // MFMA A/B frag (8 bf16)
typedef __attribute__((ext_vector_type(4))) float f32x4;     // MFMA C/D frag

static __device__ __forceinline__ float bf2f(bf16_t u) {
    return __uint_as_float(((unsigned)u) << 16);
}
static __device__ __forceinline__ bf16_t f2bf(float f) {
    unsigned u = __float_as_uint(f);
    u += 0x7FFFu + ((u >> 16) & 1u);   // round-nearest-even
    return (bf16_t)(u >> 16);
}

// =====================================================================
// MFMA GEMM:  C[M,N] = A[M,K]bf16 @ B[Npad,K]bf16^T   (m97 recipe)
// =====================================================================
template <typename TC>
__global__ __launch_bounds__(256) void gemm_mfma_bt(
    const bf16_t* __restrict__ A, const bf16_t* __restrict__ B,
    TC* __restrict__ C, int M, int N, int K)
{
    __shared__ __align__(16) bf16_t As[128 * 32];
    __shared__ __align__(16) bf16_t Bs[128 * 32];
    const int tid = threadIdx.x;
    const int m0 = blockIdx.y * 128;
    const int n0 = blockIdx.x * 128;
    const int wid = tid >> 6;
    const int lane = tid & 63;
    const int wr = (wid >> 1) * 64;
    const int wc = (wid & 1) * 64;
    const int fr = lane & 15;
    const int fk = (lane >> 4) * 8;

    f32x4 acc[4][4];
    #pragma unroll
    for (int i = 0; i < 4; ++i)
        #pragma unroll
        for (int j = 0; j < 4; ++j) acc[i][j] = (f32x4){0.f, 0.f, 0.f, 0.f};

    const int srow = tid >> 2;
    const int scol = (tid & 3) * 8;
    const bf16_t* gA = A + (size_t)(m0 + srow) * K + scol;
    const bf16_t* gB = B + (size_t)(n0 + srow) * K + scol;
    bf16_t* lA = As + tid * 8;
    bf16_t* lB = Bs + tid * 8;

    for (int k0 = 0; k0 < K; k0 += 32) {
        __builtin_amdgcn_global_load_lds(
            (const __attribute__((address_space(1))) void*)(gA + k0),
            (__attribute__((address_space(3))) void*)lA, 16, 0, 0);
        __builtin_amdgcn_global_load_lds(
            (const __attribute__((address_space(1))) void*)(gA + (size_t)64 * K + k0),
            (__attribute__((address_space(3))) void*)(lA + 2048), 16, 0, 0);
        __builtin_amdgcn_global_load_lds(
            (const __attribute__((address_space(1))) void*)(gB + k0),
            (__attribute__((address_space(3))) void*)lB, 16, 0, 0);
        __builtin_amdgcn_global_load_lds(
            (const __attribute__((address_space(1))) void*)(gB + (size_t)64 * K + k0),
            (__attribute__((address_space(3))) void*)(lB + 2048), 16, 0, 0);
        __syncthreads();

        short8v a_frag[4], b_frag[4];
        #pragma unroll
        for (int m = 0; m < 4; ++m)
            a_frag[m] = *(const short8v*)&As[(wr + m * 16 + fr) * 32 + fk];
        #pragma unroll
        for (int n = 0; n < 4; ++n)
            b_frag[n] = *(const short8v*)&Bs[(wc + n * 16 + fr) * 32 + fk];
        #pragma unroll
        for (int m = 0; m < 4; ++m)
            #pragma unroll
            for (int n = 0; n < 4; ++n)
                acc[m][n] = __builtin_amdgcn_mfma_f32_16x16x32_bf16(
                    a_frag[m], b_frag[n], acc[m][n], 0, 0, 0);
        __syncthreads();
    }

    #pragma unroll
    for (int mi = 0; mi < 4; ++mi) {
        #pragma unroll
        for (int ni = 0; ni < 4; ++ni) {
            const int col = n0 + wc + ni * 16 + fr;
            if (col < N) {
                #pragma unroll
                for (int q = 0; q < 4; ++q) {
                    const int row = m0 + wr + mi * 16 + (lane >> 4) * 4 + q;
                    if constexpr (sizeof(TC) == 2)
                        C[(size_t)row * N + col] = f2bf(acc[mi][ni][q]);
                    else
                        C[(size_t)row * N + col] = acc[mi][ni][q];
                }
            }
        }
    }
}

// =====================================================================
__global__ __launch_bounds__(256) void cvt_bf16_kernel(
    const float* __restrict__ in, bf16_t* __restrict__ out, int n)
{
    const int base = (blockIdx.x * 256 + threadIdx.x) * 4;
    if (base >= n) return;
    float4 v = *(const float4*)&in[base];
    ushort4 o;
    o.x = f2bf(v.x); o.y = f2bf(v.y); o.z = f2bf(v.z); o.w = f2bf(v.w);
    *(ushort4*)&out[base] = o;
}

__global__ __launch_bounds__(256) void wpad_kernel(
    const float* __restrict__ W, bf16_t* __restrict__ Wp,
    int N, int Npad, int K)
{
    const int i = blockIdx.x * 256 + threadIdx.x;
    if (i >= Npad * K) return;
    const int r = i / K, k = i - r * K;
    Wp[i] = (r < N) ? f2bf(W[(size_t)r * K + k]) : (bf16_t)0;
}

// =====================================================================
__global__ __launch_bounds__(256) void dt_kernel(
    const bf16_t* __restrict__ zx, const float* __restrict__ dt_bias,
    float* __restrict__ dtbuf)
{
    const int idx = blockIdx.x * 256 + threadIdx.x;   // < 32768*8
    const int h = idx & 7;
    const int row = idx >> 3;
    const float v = bf2f(zx[(size_t)row * DPROJ + (DINNER + CONVD) + h]) + dt_bias[h];
    const float sp = (v > 0.f) ? (v + log1pf(expf(-v))) : log1pf(expf(v));
    dtbuf[idx] = sp;
}

// =====================================================================
__global__ __launch_bounds__(256) void conv_silu_kernel(
    const bf16_t* __restrict__ zx,
    const float* __restrict__ wA, const float* __restrict__ bA,
    const float* __restrict__ wB, const float* __restrict__ bB,
    bf16_t* __restrict__ out)
{
    const int idx = blockIdx.x * 256 + threadIdx.x;   // < 4*8192*640
    const int c = idx % CONVD;
    const int t = idx / CONVD;
    const int l = t & (LSEQ - 1);
    const int b = t >> 13;
    const int hh = l >> 7;
    const int ww = l & (WW - 1);
    const float* wp = (b < 2) ? wA : wB;
    const float* bp = (b < 2) ? bA : bB;
    const float* w9 = wp + c * 9;
    float acc = bp[c];
    #pragma unroll
    for (int ki = -1; ki <= 1; ++ki) {
        const int hi = hh + ki;
        if ((unsigned)hi >= (unsigned)HH) continue;
        #pragma unroll
        for (int kj = -1; kj <= 1; ++kj) {
            const int wi = ww + kj;
            if ((unsigned)wi >= (unsigned)WW) continue;
            const size_t off = ((size_t)(b * LSEQ + hi * WW + wi)) * DPROJ + DINNER + c;
            acc += bf2f(zx[off]) * w9[(ki + 1) * 3 + (kj + 1)];
        }
    }
    out[idx] = f2bf(acc / (1.f + expf(-acc)));  // silu
}

// =====================================================================
// KV partials: KVp[chunk][(b*8+h)*4096 + s*64 + p] =
//   sum_{l in chunk} B[b,l,s] * x[b,l,h,p] * dt[b,l,h]*exp(A_log[h])
// grid (KVCH=32, 8, 4), block 128 = 2 waves. Each wave: 4 tiles of 32
// rows; per lane 4s x 16p register tile (64 FMA per 5 ds_read_b128).
// Wave 0 dumps acc to LDS, wave 1 adds and stores the block partial.
// =====================================================================
__global__ __launch_bounds__(128) void kv_part_kernel(
    const bf16_t* __restrict__ xconv, const float* __restrict__ dtbuf,
    const float* __restrict__ A_log, float* __restrict__ KVp)
{
    const int h = blockIdx.y, b = blockIdx.z, chunk = blockIdx.x;
    const int tid = threadIdx.x;
    const int w = tid >> 6, lane = tid & 63;
    // per-wave region: Bt[32][68] @ wbase, Xt[32][68] @ wbase+2176
    __shared__ float lds[2 * 4352];
    float* Bt = lds + w * 4352;
    float* Xt = Bt + 2176;
    const float eA = expf(A_log[h]);
    const int s4  = (lane & 15) * 4;
    const int p16 = (lane >> 4) * 16;
    const int r    = lane & 31;   // staging row within tile
    const int part = lane >> 5;   // 0: B cols, 1: x cols

    float acc[4][16];
    #pragma unroll
    for (int i = 0; i < 4; ++i)
        #pragma unroll
        for (int j = 0; j < 16; ++j) acc[i][j] = 0.f;

    const int l0 = b * LSEQ + chunk * 256;

    for (int t = 0; t < 8; t += 2) {          // wave w: tiles t+w
        const int row = l0 + (t + w) * 32 + r;
        const bf16_t* src = xconv + (size_t)row * CONVD + (part ? h * 64 : DINNER);
        const float scale = part ? dtbuf[row * NH + h] * eA : 1.f;
        float* dst = part ? &Xt[r * 68] : &Bt[r * 68];
        #pragma unroll
        for (int j = 0; j < 8; ++j) {
            ushort8v v = *(const ushort8v*)(src + j * 8);
            f32x4 lo = {bf2f(v[0]) * scale, bf2f(v[1]) * scale,
                        bf2f(v[2]) * scale, bf2f(v[3]) * scale};
            f32x4 hi = {bf2f(v[4]) * scale, bf2f(v[5]) * scale,
                        bf2f(v[6]) * scale, bf2f(v[7]) * scale};
            *(f32x4*)&dst[j * 8]     = lo;
            *(f32x4*)&dst[j * 8 + 4] = hi;
        }
        __syncthreads();
        #pragma unroll 4
        for (int rr = 0; rr < 32; ++rr) {
            const f32x4 bv = *(const f32x4*)&Bt[rr * 68 + s4];
            #pragma unroll
            for (int q = 0; q < 4; ++q) {
                const f32x4 xv = *(const f32x4*)&Xt[rr * 68 + p16 + q * 4];
                #pragma unroll
                for (int si = 0; si < 4; ++si)
                    #pragma unroll
                    for (int k = 0; k < 4; ++k)
                        acc[si][q * 4 + k] += bv[si] * xv[k];
            }
        }
        __syncthreads();
    }

    // combine the two waves' partials (stride-68 scratch to dodge banks)
    if (w == 0) {
        #pragma unroll
        for (int si = 0; si < 4; ++si)
            #pragma unroll
            for (int q = 0; q < 4; ++q)
                *(f32x4*)&lds[(s4 + si) * 68 + p16 + q * 4] =
                    (f32x4){acc[si][q*4], acc[si][q*4+1], acc[si][q*4+2], acc[si][q*4+3]};
    }
    __syncthreads();
    if (w == 1) {
        float* dst = KVp + ((size_t)chunk * (NB * NH) + (b * NH + h)) * 4096;
        #pragma unroll
        for (int si = 0; si < 4; ++si)
            #pragma unroll
            for (int q = 0; q < 4; ++q) {
                const f32x4 o = *(const f32x4*)&lds[(s4 + si) * 68 + p16 + q * 4];
                f32x4 v = {acc[si][q*4] + o[0], acc[si][q*4+1] + o[1],
                           acc[si][q*4+2] + o[2], acc[si][q*4+3] + o[3]};
                *(f32x4*)&dst[(s4 + si) * 64 + p16 + q * 4] = v;
            }
    }
}

// =====================================================================
// KV[idx] = sum_chunk KVp[chunk][idx]   (idx < 4*8*64*64 = 131072)
// =====================================================================
__global__ __launch_bounds__(256) void kv_reduce_kernel(
    const float* __restrict__ KVp, float* __restrict__ KV)
{
    const int idx = blockIdx.x * 256 + threadIdx.x;
    float s = 0.f;
    #pragma unroll
    for (int c = 0; c < KVCH; ++c) s += KVp[(size_t)c * 131072 + idx];
    KV[idx] = s;
}

// =====================================================================
// y = C·KV + x·D -> LayerNorm -> *g+b -> *z -> ybuf (bf16)
// =====================================================================
#define YROWS 16
__global__ __launch_bounds__(512) void yln_kernel(
    const bf16_t* __restrict__ xconv, const float* __restrict__ KV,
    const float* __restrict__ DA, const float* __restrict__ DB,
    const float* __restrict__ ln_g, const float* __restrict__ ln_b,
    const bf16_t* __restrict__ zsrc, bf16_t* __restrict__ ybuf)
{
    const int b = blockIdx.y;
    const int row0 = blockIdx.x * YROWS;
    const int c = threadIdx.x;
    const int h = c >> 6, p = c & 63;
    float kv[64];
    const float* kvp = KV + ((size_t)(b * NH + h) * 64) * 64 + p;
    #pragma unroll
    for (int s = 0; s < 64; ++s) kv[s] = kvp[s * 64];
    const float Dv = (b < 2) ? DA[h] : DB[h];
    const float g = ln_g[c], be = ln_b[c];
    __shared__ float Cl[64];
    __shared__ float red[2][8];

    for (int r = 0; r < YROWS; ++r) {
        const int row = b * LSEQ + row0 + r;
        if (c < 64) Cl[c] = bf2f(xconv[(size_t)row * CONVD + DINNER + DSTATE + c]);
        __syncthreads();
        const float x = bf2f(xconv[(size_t)row * CONVD + c]);
        float y = x * Dv;
        #pragma unroll
        for (int s = 0; s < 64; ++s) y += Cl[s] * kv[s];
        float s1 = y, s2 = y * y;
        #pragma unroll
        for (int off = 32; off > 0; off >>= 1) {
            s1 += __shfl_xor(s1, off, 64);
            s2 += __shfl_xor(s2, off, 64);
        }
        if ((c & 63) == 0) { red[0][c >> 6] = s1; red[1][c >> 6] = s2; }
        __syncthreads();
        float t1 = 0.f, t2 = 0.f;
        #pragma unroll
        for (int w2 = 0; w2 < 8; ++w2) { t1 += red[0][w2]; t2 += red[1][w2]; }
        const float mu = t1 * (1.f / 512.f);
        const float var = t2 * (1.f / 512.f) - mu * mu;
        const float rstd = rsqrtf(var + 1e-5f);
        const float z = bf2f(zsrc[(size_t)row * DPROJ + c]);
        ybuf[(size_t)row * DINNER + c] = f2bf(((y - mu) * rstd * g + be) * z);
        __syncthreads();
    }
}

// =====================================================================
extern "C" void kernel_launch(void* const* d_in, const int* in_sizes, int n_in,
                              void* d_out, int out_size, void* d_ws, size_t ws_size,
                              hipStream_t stream)
{
    const float* u        = (const float*)d_in[0];
    const float* W_in     = (const float*)d_in[3];
    const float* W_st     = (const float*)d_in[4];
    const float* conv_l_w = (const float*)d_in[5];
    const float* conv_l_b = (const float*)d_in[6];
    const float* conv_r_w = (const float*)d_in[7];
    const float* conv_r_b = (const float*)d_in[8];
    const float* conv_w   = (const float*)d_in[9];
    const float* conv_b   = (const float*)d_in[10];
    const float* dt_bias  = (const float*)d_in[11];
    const float* A_log    = (const float*)d_in[12];
    const float* D_l      = (const float*)d_in[13];
    const float* D_r      = (const float*)d_in[14];
    const float* Dp       = (const float*)d_in[15];
    const float* ln_g     = (const float*)d_in[16];
    const float* ln_b     = (const float*)d_in[17];
    const float* W_out    = (const float*)d_in[18];
    float* out = (float*)d_out;

    // ---- workspace layout: ~172 MB (KVp aliases ubf: both 16,777,216 B) ----
    char* ws = (char*)d_ws;
    const size_t ZX_B    = (size_t)MROWS * DPROJ * 2;   //  76,021,760
    const size_t XCONV_B = (size_t)MROWS * CONVD * 2;   //  41,943,040
    const size_t YBUF_B  = (size_t)MROWS * DINNER * 2;  //  33,554,432
    const size_t DT_B    = (size_t)MROWS * NH * 4;      //   1,048,576
    const size_t KV_B    = (size_t)NB * NH * 64 * 64 * 4; //   524,288
    const size_t UBF_B   = (size_t)MROWS * DMODEL * 2;  //  16,777,216 (== KVCH*131072*4)
    const size_t WIN_B   = (size_t)1280 * DMODEL * 2;
    const size_t WST_B   = (size_t)1280 * DINNER * 2;
    bf16_t* zx    = (bf16_t*)(ws);
    bf16_t* xconv = (bf16_t*)(ws + ZX_B);
    bf16_t* ybuf  = (bf16_t*)(ws + ZX_B + XCONV_B);
    float*  dtbuf = (float*) (ws + ZX_B + XCONV_B + YBUF_B);
    float*  KV    = (float*) (ws + ZX_B + XCONV_B + YBUF_B + DT_B);
    bf16_t* ubf   = (bf16_t*)(ws + ZX_B + XCONV_B + YBUF_B + DT_B + KV_B);
    float*  KVp   = (float*) (ws + ZX_B + XCONV_B + YBUF_B + DT_B + KV_B);  // alias (dead after gemm1)
    bf16_t* WinP  = (bf16_t*)(ws + ZX_B + XCONV_B + YBUF_B + DT_B + KV_B + UBF_B);
    bf16_t* WstP  = (bf16_t*)(ws + ZX_B + XCONV_B + YBUF_B + DT_B + KV_B + UBF_B + WIN_B);
    bf16_t* WoutP = (bf16_t*)(ws + ZX_B + XCONV_B + YBUF_B + DT_B + KV_B + UBF_B + WIN_B + WST_B);

    const dim3 gemmGridP(10, MROWS / 128);   // Npad=1280
    const dim3 gemmGridO(2,  MROWS / 128);   // N=256
    const dim3 kvGrid(KVCH, NH, NB);
    const dim3 ylnGrid(LSEQ / YROWS, NB);

    // ---- one-time conversions ----
    cvt_bf16_kernel<<<(MROWS * DMODEL / 4 + 255) / 256, 256, 0, stream>>>(u, ubf, MROWS * DMODEL);
    wpad_kernel<<<(1280 * DMODEL + 255) / 256, 256, 0, stream>>>(W_in, WinP, DPROJ, 1280, DMODEL);
    wpad_kernel<<<(1280 * DINNER + 255) / 256, 256, 0, stream>>>(W_st, WstP, DPROJ, 1280, DINNER);
    wpad_kernel<<<(256 * DINNER + 255) / 256, 256, 0, stream>>>(W_out, WoutP, DMODEL, 256, DINNER);

    // ---------------- pass 1 ----------------
    gemm_mfma_bt<bf16_t><<<gemmGridP, 256, 0, stream>>>(ubf, WinP, zx, MROWS, DPROJ, DMODEL);
    dt_kernel<<<(MROWS * NH) / 256, 256, 0, stream>>>(zx, dt_bias, dtbuf);
    conv_silu_kernel<<<(MROWS * CONVD) / 256, 256, 0, stream>>>(
        zx, conv_l_w, conv_l_b, conv_r_w, conv_r_b, xconv);
    kv_part_kernel<<<kvGrid, 128, 0, stream>>>(xconv, dtbuf, A_log, KVp);   // KVp overwrites ubf (dead)
    kv_reduce_kernel<<<131072 / 256, 256, 0, stream>>>(KVp, KV);
    yln_kernel<<<ylnGrid, 512, 0, stream>>>(xconv, KV, D_l, D_r, ln_g, ln_b, zx, ybuf);

    // ---------------- pass 2 ----------------
    gemm_mfma_bt<bf16_t><<<gemmGridP, 256, 0, stream>>>(ybuf, WstP, zx, MROWS, DPROJ, DINNER);
    dt_kernel<<<(MROWS * NH) / 256, 256, 0, stream>>>(zx, dt_bias, dtbuf);
    conv_silu_kernel<<<(MROWS * CONVD) / 256, 256, 0, stream>>>(
        zx, conv_w, conv_b, conv_w, conv_b, xconv);
    kv_part_kernel<<<kvGrid, 128, 0, stream>>>(xconv, dtbuf, A_log, KVp);
    kv_reduce_kernel<<<131072 / 256, 256, 0, stream>>>(KVp, KV);
    yln_kernel<<<ylnGrid, 512, 0, stream>>>(xconv, KV, Dp, Dp, ln_g, ln_b, zx, ybuf);

    // ---------------- output projection ----------------
    gemm_mfma_bt<float><<<gemmGridO, 256, 0, stream>>>(ybuf, WoutP, out, MROWS, DMODEL, DINNER);
}

// Round 6
// 605.254 us; speedup vs baseline: 2.9507x; 1.3016x over previous
//
#include <hip/hip_runtime.h>
#include <hip/hip_bf16.h>
#include <math.h>

// ---- problem constants ----
#define NB    4          // batch
#define LSEQ  8192       // H*W
#define HH    64
#define WW    128
#define DMODEL 256
#define DINNER 512
#define NH    8          // heads
#define DSTATE 64
#define DPROJ 1160       // 2*512 + 2*64 + 8
#define CONVD 640        // 512 + 128
#define MROWS (NB*LSEQ)  // 32768
#define KVCH  32         // l-chunks per (b,h) in kv_part
#define CBLK  80         // 640/8 channel-blocks per position

typedef unsigned short bf16_t;
typedef __attribute__((ext_vector_type(8))) unsigned short ushort8v;
typedef __attribute__((ext_vector_type(8))) short short8v;   // MFMA A/B frag (8 bf16)
typedef __attribute__((ext_vector_type(4))) float f32x4;     // MFMA C/D frag

static __device__ __forceinline__ float bf2f(bf16_t u) {
    return __uint_as_float(((unsigned)u) << 16);
}
static __device__ __forceinline__ bf16_t f2bf(float f) {
    unsigned u = __float_as_uint(f);
    u += 0x7FFFu + ((u >> 16) & 1u);   // round-nearest-even
    return (bf16_t)(u >> 16);
}

// =====================================================================
// MFMA GEMM:  C[M,N] = A[M,K]bf16 @ B[Npad,K]bf16^T   (m97 recipe)
// =====================================================================
template <typename TC>
__global__ __launch_bounds__(256) void gemm_mfma_bt(
    const bf16_t* __restrict__ A, const bf16_t* __restrict__ B,
    TC* __restrict__ C, int M, int N, int K)
{
    __shared__ __align__(16) bf16_t As[128 * 32];
    __shared__ __align__(16) bf16_t Bs[128 * 32];
    const int tid = threadIdx.x;
    const int m0 = blockIdx.y * 128;
    const int n0 = blockIdx.x * 128;
    const int wid = tid >> 6;
    const int lane = tid & 63;
    const int wr = (wid >> 1) * 64;
    const int wc = (wid & 1) * 64;
    const int fr = lane & 15;
    const int fk = (lane >> 4) * 8;

    f32x4 acc[4][4];
    #pragma unroll
    for (int i = 0; i < 4; ++i)
        #pragma unroll
        for (int j = 0; j < 4; ++j) acc[i][j] = (f32x4){0.f, 0.f, 0.f, 0.f};

    const int srow = tid >> 2;
    const int scol = (tid & 3) * 8;
    const bf16_t* gA = A + (size_t)(m0 + srow) * K + scol;
    const bf16_t* gB = B + (size_t)(n0 + srow) * K + scol;
    bf16_t* lA = As + tid * 8;
    bf16_t* lB = Bs + tid * 8;

    for (int k0 = 0; k0 < K; k0 += 32) {
        __builtin_amdgcn_global_load_lds(
            (const __attribute__((address_space(1))) void*)(gA + k0),
            (__attribute__((address_space(3))) void*)lA, 16, 0, 0);
        __builtin_amdgcn_global_load_lds(
            (const __attribute__((address_space(1))) void*)(gA + (size_t)64 * K + k0),
            (__attribute__((address_space(3))) void*)(lA + 2048), 16, 0, 0);
        __builtin_amdgcn_global_load_lds(
            (const __attribute__((address_space(1))) void*)(gB + k0),
            (__attribute__((address_space(3))) void*)lB, 16, 0, 0);
        __builtin_amdgcn_global_load_lds(
            (const __attribute__((address_space(1))) void*)(gB + (size_t)64 * K + k0),
            (__attribute__((address_space(3))) void*)(lB + 2048), 16, 0, 0);
        __syncthreads();

        short8v a_frag[4], b_frag[4];
        #pragma unroll
        for (int m = 0; m < 4; ++m)
            a_frag[m] = *(const short8v*)&As[(wr + m * 16 + fr) * 32 + fk];
        #pragma unroll
        for (int n = 0; n < 4; ++n)
            b_frag[n] = *(const short8v*)&Bs[(wc + n * 16 + fr) * 32 + fk];
        #pragma unroll
        for (int m = 0; m < 4; ++m)
            #pragma unroll
            for (int n = 0; n < 4; ++n)
                acc[m][n] = __builtin_amdgcn_mfma_f32_16x16x32_bf16(
                    a_frag[m], b_frag[n], acc[m][n], 0, 0, 0);
        __syncthreads();
    }

    #pragma unroll
    for (int mi = 0; mi < 4; ++mi) {
        #pragma unroll
        for (int ni = 0; ni < 4; ++ni) {
            const int col = n0 + wc + ni * 16 + fr;
            if (col < N) {
                #pragma unroll
                for (int q = 0; q < 4; ++q) {
                    const int row = m0 + wr + mi * 16 + (lane >> 4) * 4 + q;
                    if constexpr (sizeof(TC) == 2)
                        C[(size_t)row * N + col] = f2bf(acc[mi][ni][q]);
                    else
                        C[(size_t)row * N + col] = acc[mi][ni][q];
                }
            }
        }
    }
}

// =====================================================================
__global__ __launch_bounds__(256) void cvt_bf16_kernel(
    const float* __restrict__ in, bf16_t* __restrict__ out, int n)
{
    const int base = (blockIdx.x * 256 + threadIdx.x) * 4;
    if (base >= n) return;
    float4 v = *(const float4*)&in[base];
    ushort4 o;
    o.x = f2bf(v.x); o.y = f2bf(v.y); o.z = f2bf(v.z); o.w = f2bf(v.w);
    *(ushort4*)&out[base] = o;
}

__global__ __launch_bounds__(256) void wpad_kernel(
    const float* __restrict__ W, bf16_t* __restrict__ Wp,
    int N, int Npad, int K)
{
    const int i = blockIdx.x * 256 + threadIdx.x;
    if (i >= Npad * K) return;
    const int r = i / K, k = i - r * K;
    Wp[i] = (r < N) ? f2bf(W[(size_t)r * K + k]) : (bf16_t)0;
}

// =====================================================================
__global__ __launch_bounds__(256) void dt_kernel(
    const bf16_t* __restrict__ zx, const float* __restrict__ dt_bias,
    float* __restrict__ dtbuf)
{
    const int idx = blockIdx.x * 256 + threadIdx.x;   // < 32768*8
    const int h = idx & 7;
    const int row = idx >> 3;
    const float v = bf2f(zx[(size_t)row * DPROJ + (DINNER + CONVD) + h]) + dt_bias[h];
    const float sp = (v > 0.f) ? (v + log1pf(expf(-v))) : log1pf(expf(v));
    dtbuf[idx] = sp;
}

// =====================================================================
// 3x3 depthwise conv + bias + SiLU, channel-vectorized x8.
// thread = (spatial position t, channel block c0..c0+7).
// 9 taps x ushort8v load + 8 FMA; weights in 72 regs (loop-invariant).
// =====================================================================
__global__ __launch_bounds__(256) void conv_silu_kernel(
    const bf16_t* __restrict__ zx,
    const float* __restrict__ wA, const float* __restrict__ bA,
    const float* __restrict__ wB, const float* __restrict__ bB,
    bf16_t* __restrict__ out)
{
    const int idx = blockIdx.x * 256 + threadIdx.x;   // < 32768*80
    const int cb = idx % CBLK;
    const int t  = idx / CBLK;
    const int c0 = cb * 8;
    const int l = t & (LSEQ - 1);
    const int b = t >> 13;
    const int hh = l >> 7;
    const int ww = l & (WW - 1);
    const float* wp = (b < 2) ? wA : wB;
    const float* bp = (b < 2) ? bA : bB;

    // 8 channels x 9 taps of weights -> registers (18 x float4)
    float w[72];
    const float4* wsrc = (const float4*)(wp + c0 * 9);
    #pragma unroll
    for (int i = 0; i < 18; ++i) ((float4*)w)[i] = wsrc[i];

    float acc[8];
    float4 bv0 = *(const float4*)(bp + c0);
    float4 bv1 = *(const float4*)(bp + c0 + 4);
    acc[0] = bv0.x; acc[1] = bv0.y; acc[2] = bv0.z; acc[3] = bv0.w;
    acc[4] = bv1.x; acc[5] = bv1.y; acc[6] = bv1.z; acc[7] = bv1.w;

    const bf16_t* base = zx + (size_t)b * LSEQ * DPROJ + DINNER + c0;
    #pragma unroll
    for (int ki = -1; ki <= 1; ++ki) {
        const int hi = hh + ki;
        if ((unsigned)hi >= (unsigned)HH) continue;
        #pragma unroll
        for (int kj = -1; kj <= 1; ++kj) {
            const int wi = ww + kj;
            if ((unsigned)wi >= (unsigned)WW) continue;
            const ushort8v v = *(const ushort8v*)(base + (size_t)(hi * WW + wi) * DPROJ);
            const int tap = (ki + 1) * 3 + (kj + 1);
            #pragma unroll
            for (int q = 0; q < 8; ++q) acc[q] += bf2f(v[q]) * w[q * 9 + tap];
        }
    }
    ushort8v o;
    #pragma unroll
    for (int q = 0; q < 8; ++q) {
        const float s = acc[q] / (1.f + expf(-acc[q]));   // silu
        o[q] = f2bf(s);
    }
    *(ushort8v*)(out + (size_t)t * CONVD + c0) = o;
}

// =====================================================================
// KV partials: KVp[chunk][(b*8+h)*4096 + s*64 + p]
// =====================================================================
__global__ __launch_bounds__(128) void kv_part_kernel(
    const bf16_t* __restrict__ xconv, const float* __restrict__ dtbuf,
    const float* __restrict__ A_log, float* __restrict__ KVp)
{
    const int h = blockIdx.y, b = blockIdx.z, chunk = blockIdx.x;
    const int tid = threadIdx.x;
    const int w = tid >> 6, lane = tid & 63;
    __shared__ float lds[2 * 4352];
    float* Bt = lds + w * 4352;
    float* Xt = Bt + 2176;
    const float eA = expf(A_log[h]);
    const int s4  = (lane & 15) * 4;
    const int p16 = (lane >> 4) * 16;
    const int r    = lane & 31;
    const int part = lane >> 5;

    float acc[4][16];
    #pragma unroll
    for (int i = 0; i < 4; ++i)
        #pragma unroll
        for (int j = 0; j < 16; ++j) acc[i][j] = 0.f;

    const int l0 = b * LSEQ + chunk * 256;

    for (int t = 0; t < 8; t += 2) {
        const int row = l0 + (t + w) * 32 + r;
        const bf16_t* src = xconv + (size_t)row * CONVD + (part ? h * 64 : DINNER);
        const float scale = part ? dtbuf[row * NH + h] * eA : 1.f;
        float* dst = part ? &Xt[r * 68] : &Bt[r * 68];
        #pragma unroll
        for (int j = 0; j < 8; ++j) {
            ushort8v v = *(const ushort8v*)(src + j * 8);
            f32x4 lo = {bf2f(v[0]) * scale, bf2f(v[1]) * scale,
                        bf2f(v[2]) * scale, bf2f(v[3]) * scale};
            f32x4 hi = {bf2f(v[4]) * scale, bf2f(v[5]) * scale,
                        bf2f(v[6]) * scale, bf2f(v[7]) * scale};
            *(f32x4*)&dst[j * 8]     = lo;
            *(f32x4*)&dst[j * 8 + 4] = hi;
        }
        __syncthreads();
        #pragma unroll 4
        for (int rr = 0; rr < 32; ++rr) {
            const f32x4 bv = *(const f32x4*)&Bt[rr * 68 + s4];
            #pragma unroll
            for (int q = 0; q < 4; ++q) {
                const f32x4 xv = *(const f32x4*)&Xt[rr * 68 + p16 + q * 4];
                #pragma unroll
                for (int si = 0; si < 4; ++si)
                    #pragma unroll
                    for (int k = 0; k < 4; ++k)
                        acc[si][q * 4 + k] += bv[si] * xv[k];
            }
        }
        __syncthreads();
    }

    if (w == 0) {
        #pragma unroll
        for (int si = 0; si < 4; ++si)
            #pragma unroll
            for (int q = 0; q < 4; ++q)
                *(f32x4*)&lds[(s4 + si) * 68 + p16 + q * 4] =
                    (f32x4){acc[si][q*4], acc[si][q*4+1], acc[si][q*4+2], acc[si][q*4+3]};
    }
    __syncthreads();
    if (w == 1) {
        float* dst = KVp + ((size_t)chunk * (NB * NH) + (b * NH + h)) * 4096;
        #pragma unroll
        for (int si = 0; si < 4; ++si)
            #pragma unroll
            for (int q = 0; q < 4; ++q) {
                const f32x4 o = *(const f32x4*)&lds[(s4 + si) * 68 + p16 + q * 4];
                f32x4 v = {acc[si][q*4] + o[0], acc[si][q*4+1] + o[1],
                           acc[si][q*4+2] + o[2], acc[si][q*4+3] + o[3]};
                *(f32x4*)&dst[(s4 + si) * 64 + p16 + q * 4] = v;
            }
    }
}

// =====================================================================
__global__ __launch_bounds__(256) void kv_reduce_kernel(
    const float* __restrict__ KVp, float* __restrict__ KV)
{
    const int idx = blockIdx.x * 256 + threadIdx.x;
    float s = 0.f;
    #pragma unroll
    for (int c = 0; c < KVCH; ++c) s += KVp[(size_t)c * 131072 + idx];
    KV[idx] = s;
}

// =====================================================================
// y = C·KV + x·D -> LayerNorm -> *g+b -> *z -> ybuf (bf16)
// =====================================================================
#define YROWS 16
__global__ __launch_bounds__(512) void yln_kernel(
    const bf16_t* __restrict__ xconv, const float* __restrict__ KV,
    const float* __restrict__ DA, const float* __restrict__ DB,
    const float* __restrict__ ln_g, const float* __restrict__ ln_b,
    const bf16_t* __restrict__ zsrc, bf16_t* __restrict__ ybuf)
{
    const int b = blockIdx.y;
    const int row0 = blockIdx.x * YROWS;
    const int c = threadIdx.x;
    const int h = c >> 6, p = c & 63;
    float kv[64];
    const float* kvp = KV + ((size_t)(b * NH + h) * 64) * 64 + p;
    #pragma unroll
    for (int s = 0; s < 64; ++s) kv[s] = kvp[s * 64];
    const float Dv = (b < 2) ? DA[h] : DB[h];
    const float g = ln_g[c], be = ln_b[c];
    __shared__ float Cl[64];
    __shared__ float red[2][8];

    for (int r = 0; r < YROWS; ++r) {
        const int row = b * LSEQ + row0 + r;
        if (c < 64) Cl[c] = bf2f(xconv[(size_t)row * CONVD + DINNER + DSTATE + c]);
        __syncthreads();
        const float x = bf2f(xconv[(size_t)row * CONVD + c]);
        float y = x * Dv;
        #pragma unroll
        for (int s = 0; s < 64; ++s) y += Cl[s] * kv[s];
        float s1 = y, s2 = y * y;
        #pragma unroll
        for (int off = 32; off > 0; off >>= 1) {
            s1 += __shfl_xor(s1, off, 64);
            s2 += __shfl_xor(s2, off, 64);
        }
        if ((c & 63) == 0) { red[0][c >> 6] = s1; red[1][c >> 6] = s2; }
        __syncthreads();
        float t1 = 0.f, t2 = 0.f;
        #pragma unroll
        for (int w2 = 0; w2 < 8; ++w2) { t1 += red[0][w2]; t2 += red[1][w2]; }
        const float mu = t1 * (1.f / 512.f);
        const float var = t2 * (1.f / 512.f) - mu * mu;
        const float rstd = rsqrtf(var + 1e-5f);
        const float z = bf2f(zsrc[(size_t)row * DPROJ + c]);
        ybuf[(size_t)row * DINNER + c] = f2bf(((y - mu) * rstd * g + be) * z);
        __syncthreads();
    }
}

// =====================================================================
extern "C" void kernel_launch(void* const* d_in, const int* in_sizes, int n_in,
                              void* d_out, int out_size, void* d_ws, size_t ws_size,
                              hipStream_t stream)
{
    const float* u        = (const float*)d_in[0];
    const float* W_in     = (const float*)d_in[3];
    const float* W_st     = (const float*)d_in[4];
    const float* conv_l_w = (const float*)d_in[5];
    const float* conv_l_b = (const float*)d_in[6];
    const float* conv_r_w = (const float*)d_in[7];
    const float* conv_r_b = (const float*)d_in[8];
    const float* conv_w   = (const float*)d_in[9];
    const float* conv_b   = (const float*)d_in[10];
    const float* dt_bias  = (const float*)d_in[11];
    const float* A_log    = (const float*)d_in[12];
    const float* D_l      = (const float*)d_in[13];
    const float* D_r      = (const float*)d_in[14];
    const float* Dp       = (const float*)d_in[15];
    const float* ln_g     = (const float*)d_in[16];
    const float* ln_b     = (const float*)d_in[17];
    const float* W_out    = (const float*)d_in[18];
    float* out = (float*)d_out;

    // ---- workspace layout: ~172 MB (KVp aliases ubf) ----
    char* ws = (char*)d_ws;
    const size_t ZX_B    = (size_t)MROWS * DPROJ * 2;
    const size_t XCONV_B = (size_t)MROWS * CONVD * 2;
    const size_t YBUF_B  = (size_t)MROWS * DINNER * 2;
    const size_t DT_B    = (size_t)MROWS * NH * 4;
    const size_t KV_B    = (size_t)NB * NH * 64 * 64 * 4;
    const size_t UBF_B   = (size_t)MROWS * DMODEL * 2;   // == KVCH*131072*4
    const size_t WIN_B   = (size_t)1280 * DMODEL * 2;
    const size_t WST_B   = (size_t)1280 * DINNER * 2;
    bf16_t* zx    = (bf16_t*)(ws);
    bf16_t* xconv = (bf16_t*)(ws + ZX_B);
    bf16_t* ybuf  = (bf16_t*)(ws + ZX_B + XCONV_B);
    float*  dtbuf = (float*) (ws + ZX_B + XCONV_B + YBUF_B);
    float*  KV    = (float*) (ws + ZX_B + XCONV_B + YBUF_B + DT_B);
    bf16_t* ubf   = (bf16_t*)(ws + ZX_B + XCONV_B + YBUF_B + DT_B + KV_B);
    float*  KVp   = (float*) (ws + ZX_B + XCONV_B + YBUF_B + DT_B + KV_B);  // alias (ubf dead after gemm1)
    bf16_t* WinP  = (bf16_t*)(ws + ZX_B + XCONV_B + YBUF_B + DT_B + KV_B + UBF_B);
    bf16_t* WstP  = (bf16_t*)(ws + ZX_B + XCONV_B + YBUF_B + DT_B + KV_B + UBF_B + WIN_B);
    bf16_t* WoutP = (bf16_t*)(ws + ZX_B + XCONV_B + YBUF_B + DT_B + KV_B + UBF_B + WIN_B + WST_B);

    const dim3 gemmGridP(10, MROWS / 128);   // Npad=1280
    const dim3 gemmGridO(2,  MROWS / 128);   // N=256
    const dim3 kvGrid(KVCH, NH, NB);
    const dim3 ylnGrid(LSEQ / YROWS, NB);
    const int convGrid = MROWS * CBLK / 256; // 10240

    // ---- one-time conversions ----
    cvt_bf16_kernel<<<(MROWS * DMODEL / 4 + 255) / 256, 256, 0, stream>>>(u, ubf, MROWS * DMODEL);
    wpad_kernel<<<(1280 * DMODEL + 255) / 256, 256, 0, stream>>>(W_in, WinP, DPROJ, 1280, DMODEL);
    wpad_kernel<<<(1280 * DINNER + 255) / 256, 256, 0, stream>>>(W_st, WstP, DPROJ, 1280, DINNER);
    wpad_kernel<<<(256 * DINNER + 255) / 256, 256, 0, stream>>>(W_out, WoutP, DMODEL, 256, DINNER);

    // ---------------- pass 1 ----------------
    gemm_mfma_bt<bf16_t><<<gemmGridP, 256, 0, stream>>>(ubf, WinP, zx, MROWS, DPROJ, DMODEL);
    dt_kernel<<<(MROWS * NH) / 256, 256, 0, stream>>>(zx, dt_bias, dtbuf);
    conv_silu_kernel<<<convGrid, 256, 0, stream>>>(
        zx, conv_l_w, conv_l_b, conv_r_w, conv_r_b, xconv);
    kv_part_kernel<<<kvGrid, 128, 0, stream>>>(xconv, dtbuf, A_log, KVp);
    kv_reduce_kernel<<<131072 / 256, 256, 0, stream>>>(KVp, KV);
    yln_kernel<<<ylnGrid, 512, 0, stream>>>(xconv, KV, D_l, D_r, ln_g, ln_b, zx, ybuf);

    // ---------------- pass 2 ----------------
    gemm_mfma_bt<bf16_t><<<gemmGridP, 256, 0, stream>>>(ybuf, WstP, zx, MROWS, DPROJ, DINNER);
    dt_kernel<<<(MROWS * NH) / 256, 256, 0, stream>>>(zx, dt_bias, dtbuf);
    conv_silu_kernel<<<convGrid, 256, 0, stream>>>(
        zx, conv_w, conv_b, conv_w, conv_b, xconv);
    kv_part_kernel<<<kvGrid, 128, 0, stream>>>(xconv, dtbuf, A_log, KVp);
    kv_reduce_kernel<<<131072 / 256, 256, 0, stream>>>(KVp, KV);
    yln_kernel<<<ylnGrid, 512, 0, stream>>>(xconv, KV, Dp, Dp, ln_g, ln_b, zx, ybuf);

    // ---------------- output projection ----------------
    gemm_mfma_bt<float><<<gemmGridO, 256, 0, stream>>>(ybuf, WoutP, out, MROWS, DMODEL, DINNER);
}

// Round 7
// 453.697 us; speedup vs baseline: 3.9364x; 1.3340x over previous
//
#include <hip/hip_runtime.h>
#include <hip/hip_bf16.h>
#include <math.h>

// ---- problem constants ----
#define NB    4          // batch
#define LSEQ  8192       // H*W
#define HH    64
#define WW    128
#define DMODEL 256
#define DINNER 512
#define NH    8          // heads
#define DSTATE 64
#define DPROJ 1160       // 2*512 + 2*64 + 8
#define CONVD 640        // 512 + 128
#define MROWS (NB*LSEQ)  // 32768
#define KVCH  32         // l-chunks per (b,h) in kv_part
#define CBLK  80         // 640/8 channel-blocks per position

typedef unsigned short bf16_t;
typedef __attribute__((ext_vector_type(8))) unsigned short ushort8v;
typedef __attribute__((ext_vector_type(8))) short short8v;   // MFMA A/B frag (8 bf16)
typedef __attribute__((ext_vector_type(4))) float f32x4;     // MFMA C/D frag

static __device__ __forceinline__ float bf2f(bf16_t u) {
    return __uint_as_float(((unsigned)u) << 16);
}
static __device__ __forceinline__ bf16_t f2bf(float f) {
    unsigned u = __float_as_uint(f);
    u += 0x7FFFu + ((u >> 16) & 1u);   // round-nearest-even
    return (bf16_t)(u >> 16);
}

// =====================================================================
// MFMA GEMM:  C[M,N] = A[M,K]bf16 @ B[Npad,K]bf16^T   (m97 recipe)
// generalized with row strides lda/ldb/ldc and batch strides (grid.z).
// M%128==0, K%32==0, B rows padded to n-tile; C bounds-checked col<N.
// =====================================================================
template <typename TC>
__global__ __launch_bounds__(256) void gemm_mfma_bt(
    const bf16_t* __restrict__ A, int lda, size_t sAb,
    const bf16_t* __restrict__ B, int ldb, size_t sBb,
    TC* __restrict__ C, int ldc, size_t sCb,
    int M, int N, int K)
{
    __shared__ __align__(16) bf16_t As[128 * 32];
    __shared__ __align__(16) bf16_t Bs[128 * 32];
    const bf16_t* Ab = A + blockIdx.z * sAb;
    const bf16_t* Bb = B + blockIdx.z * sBb;
    TC*            Cb = C + blockIdx.z * sCb;
    const int tid = threadIdx.x;
    const int m0 = blockIdx.y * 128;
    const int n0 = blockIdx.x * 128;
    const int wid = tid >> 6;
    const int lane = tid & 63;
    const int wr = (wid >> 1) * 64;
    const int wc = (wid & 1) * 64;
    const int fr = lane & 15;
    const int fk = (lane >> 4) * 8;

    f32x4 acc[4][4];
    #pragma unroll
    for (int i = 0; i < 4; ++i)
        #pragma unroll
        for (int j = 0; j < 4; ++j) acc[i][j] = (f32x4){0.f, 0.f, 0.f, 0.f};

    const int srow = tid >> 2;
    const int scol = (tid & 3) * 8;
    const bf16_t* gA = Ab + (size_t)(m0 + srow) * lda + scol;
    const bf16_t* gB = Bb + (size_t)(n0 + srow) * ldb + scol;
    bf16_t* lA = As + tid * 8;
    bf16_t* lB = Bs + tid * 8;

    for (int k0 = 0; k0 < K; k0 += 32) {
        __builtin_amdgcn_global_load_lds(
            (const __attribute__((address_space(1))) void*)(gA + k0),
            (__attribute__((address_space(3))) void*)lA, 16, 0, 0);
        __builtin_amdgcn_global_load_lds(
            (const __attribute__((address_space(1))) void*)(gA + (size_t)64 * lda + k0),
            (__attribute__((address_space(3))) void*)(lA + 2048), 16, 0, 0);
        __builtin_amdgcn_global_load_lds(
            (const __attribute__((address_space(1))) void*)(gB + k0),
            (__attribute__((address_space(3))) void*)lB, 16, 0, 0);
        __builtin_amdgcn_global_load_lds(
            (const __attribute__((address_space(1))) void*)(gB + (size_t)64 * ldb + k0),
            (__attribute__((address_space(3))) void*)(lB + 2048), 16, 0, 0);
        __syncthreads();

        short8v a_frag[4], b_frag[4];
        #pragma unroll
        for (int m = 0; m < 4; ++m)
            a_frag[m] = *(const short8v*)&As[(wr + m * 16 + fr) * 32 + fk];
        #pragma unroll
        for (int n = 0; n < 4; ++n)
            b_frag[n] = *(const short8v*)&Bs[(wc + n * 16 + fr) * 32 + fk];
        #pragma unroll
        for (int m = 0; m < 4; ++m)
            #pragma unroll
            for (int n = 0; n < 4; ++n)
                acc[m][n] = __builtin_amdgcn_mfma_f32_16x16x32_bf16(
                    a_frag[m], b_frag[n], acc[m][n], 0, 0, 0);
        __syncthreads();
    }

    #pragma unroll
    for (int mi = 0; mi < 4; ++mi) {
        #pragma unroll
        for (int ni = 0; ni < 4; ++ni) {
            const int col = n0 + wc + ni * 16 + fr;
            if (col < N) {
                #pragma unroll
                for (int q = 0; q < 4; ++q) {
                    const int row = m0 + wr + mi * 16 + (lane >> 4) * 4 + q;
                    if constexpr (sizeof(TC) == 2)
                        Cb[(size_t)row * ldc + col] = f2bf(acc[mi][ni][q]);
                    else
                        Cb[(size_t)row * ldc + col] = acc[mi][ni][q];
                }
            }
        }
    }
}

// =====================================================================
__global__ __launch_bounds__(256) void cvt_bf16_kernel(
    const float* __restrict__ in, bf16_t* __restrict__ out, int n)
{
    const int base = (blockIdx.x * 256 + threadIdx.x) * 4;
    if (base >= n) return;
    float4 v = *(const float4*)&in[base];
    ushort4 o;
    o.x = f2bf(v.x); o.y = f2bf(v.y); o.z = f2bf(v.z); o.w = f2bf(v.w);
    *(ushort4*)&out[base] = o;
}

__global__ __launch_bounds__(256) void wpad_kernel(
    const float* __restrict__ W, bf16_t* __restrict__ Wp,
    int N, int Npad, int K)
{
    const int i = blockIdx.x * 256 + threadIdx.x;
    if (i >= Npad * K) return;
    const int r = i / K, k = i - r * K;
    Wp[i] = (r < N) ? f2bf(W[(size_t)r * K + k]) : (bf16_t)0;
}

// =====================================================================
__global__ __launch_bounds__(256) void dt_kernel(
    const bf16_t* __restrict__ zx, const float* __restrict__ dt_bias,
    float* __restrict__ dtbuf)
{
    const int idx = blockIdx.x * 256 + threadIdx.x;   // < 32768*8
    const int h = idx & 7;
    const int row = idx >> 3;
    const float v = bf2f(zx[(size_t)row * DPROJ + (DINNER + CONVD) + h]) + dt_bias[h];
    const float sp = (v > 0.f) ? (v + log1pf(expf(-v))) : log1pf(expf(v));
    dtbuf[idx] = sp;
}

// =====================================================================
// 3x3 depthwise conv + bias + SiLU, channel-vectorized x8.
// =====================================================================
__global__ __launch_bounds__(256) void conv_silu_kernel(
    const bf16_t* __restrict__ zx,
    const float* __restrict__ wA, const float* __restrict__ bA,
    const float* __restrict__ wB, const float* __restrict__ bB,
    bf16_t* __restrict__ out)
{
    const int idx = blockIdx.x * 256 + threadIdx.x;   // < 32768*80
    const int cb = idx % CBLK;
    const int t  = idx / CBLK;
    const int c0 = cb * 8;
    const int l = t & (LSEQ - 1);
    const int b = t >> 13;
    const int hh = l >> 7;
    const int ww = l & (WW - 1);
    const float* wp = (b < 2) ? wA : wB;
    const float* bp = (b < 2) ? bA : bB;

    float w[72];
    const float4* wsrc = (const float4*)(wp + c0 * 9);
    #pragma unroll
    for (int i = 0; i < 18; ++i) ((float4*)w)[i] = wsrc[i];

    float acc[8];
    float4 bv0 = *(const float4*)(bp + c0);
    float4 bv1 = *(const float4*)(bp + c0 + 4);
    acc[0] = bv0.x; acc[1] = bv0.y; acc[2] = bv0.z; acc[3] = bv0.w;
    acc[4] = bv1.x; acc[5] = bv1.y; acc[6] = bv1.z; acc[7] = bv1.w;

    const bf16_t* base = zx + (size_t)b * LSEQ * DPROJ + DINNER + c0;
    #pragma unroll
    for (int ki = -1; ki <= 1; ++ki) {
        const int hi = hh + ki;
        if ((unsigned)hi >= (unsigned)HH) continue;
        #pragma unroll
        for (int kj = -1; kj <= 1; ++kj) {
            const int wi = ww + kj;
            if ((unsigned)wi >= (unsigned)WW) continue;
            const ushort8v v = *(const ushort8v*)(base + (size_t)(hi * WW + wi) * DPROJ);
            const int tap = (ki + 1) * 3 + (kj + 1);
            #pragma unroll
            for (int q = 0; q < 8; ++q) acc[q] += bf2f(v[q]) * w[q * 9 + tap];
        }
    }
    ushort8v o;
    #pragma unroll
    for (int q = 0; q < 8; ++q) {
        const float s = acc[q] / (1.f + expf(-acc[q]));   // silu
        o[q] = f2bf(s);
    }
    *(ushort8v*)(out + (size_t)t * CONVD + c0) = o;
}

// =====================================================================
// KV partials: KVp[chunk][(b*8+h)*4096 + s*64 + p]
// =====================================================================
__global__ __launch_bounds__(128) void kv_part_kernel(
    const bf16_t* __restrict__ xconv, const float* __restrict__ dtbuf,
    const float* __restrict__ A_log, float* __restrict__ KVp)
{
    const int h = blockIdx.y, b = blockIdx.z, chunk = blockIdx.x;
    const int tid = threadIdx.x;
    const int w = tid >> 6, lane = tid & 63;
    __shared__ float lds[2 * 4352];
    float* Bt = lds + w * 4352;
    float* Xt = Bt + 2176;
    const float eA = expf(A_log[h]);
    const int s4  = (lane & 15) * 4;
    const int p16 = (lane >> 4) * 16;
    const int r    = lane & 31;
    const int part = lane >> 5;

    float acc[4][16];
    #pragma unroll
    for (int i = 0; i < 4; ++i)
        #pragma unroll
        for (int j = 0; j < 16; ++j) acc[i][j] = 0.f;

    const int l0 = b * LSEQ + chunk * 256;

    for (int t = 0; t < 8; t += 2) {
        const int row = l0 + (t + w) * 32 + r;
        const bf16_t* src = xconv + (size_t)row * CONVD + (part ? h * 64 : DINNER);
        const float scale = part ? dtbuf[row * NH + h] * eA : 1.f;
        float* dst = part ? &Xt[r * 68] : &Bt[r * 68];
        #pragma unroll
        for (int j = 0; j < 8; ++j) {
            ushort8v v = *(const ushort8v*)(src + j * 8);
            f32x4 lo = {bf2f(v[0]) * scale, bf2f(v[1]) * scale,
                        bf2f(v[2]) * scale, bf2f(v[3]) * scale};
            f32x4 hi = {bf2f(v[4]) * scale, bf2f(v[5]) * scale,
                        bf2f(v[6]) * scale, bf2f(v[7]) * scale};
            *(f32x4*)&dst[j * 8]     = lo;
            *(f32x4*)&dst[j * 8 + 4] = hi;
        }
        __syncthreads();
        #pragma unroll 4
        for (int rr = 0; rr < 32; ++rr) {
            const f32x4 bv = *(const f32x4*)&Bt[rr * 68 + s4];
            #pragma unroll
            for (int q = 0; q < 4; ++q) {
                const f32x4 xv = *(const f32x4*)&Xt[rr * 68 + p16 + q * 4];
                #pragma unroll
                for (int si = 0; si < 4; ++si)
                    #pragma unroll
                    for (int k = 0; k < 4; ++k)
                        acc[si][q * 4 + k] += bv[si] * xv[k];
            }
        }
        __syncthreads();
    }

    if (w == 0) {
        #pragma unroll
        for (int si = 0; si < 4; ++si)
            #pragma unroll
            for (int q = 0; q < 4; ++q)
                *(f32x4*)&lds[(s4 + si) * 68 + p16 + q * 4] =
                    (f32x4){acc[si][q*4], acc[si][q*4+1], acc[si][q*4+2], acc[si][q*4+3]};
    }
    __syncthreads();
    if (w == 1) {
        float* dst = KVp + ((size_t)chunk * (NB * NH) + (b * NH + h)) * 4096;
        #pragma unroll
        for (int si = 0; si < 4; ++si)
            #pragma unroll
            for (int q = 0; q < 4; ++q) {
                const f32x4 o = *(const f32x4*)&lds[(s4 + si) * 68 + p16 + q * 4];
                f32x4 v = {acc[si][q*4] + o[0], acc[si][q*4+1] + o[1],
                           acc[si][q*4+2] + o[2], acc[si][q*4+3] + o[3]};
                *(f32x4*)&dst[(s4 + si) * 64 + p16 + q * 4] = v;
            }
    }
}

// =====================================================================
// KVT[b][h*64+p][s] (bf16) = sum_chunk KVp[chunk][(b*8+h)*4096+s*64+p]
// =====================================================================
__global__ __launch_bounds__(256) void kv_reduce_T_kernel(
    const float* __restrict__ KVp, bf16_t* __restrict__ KVT)
{
    const int idx = blockIdx.x * 256 + threadIdx.x;   // < 131072
    float s = 0.f;
    #pragma unroll
    for (int c = 0; c < KVCH; ++c) s += KVp[(size_t)c * 131072 + idx];
    const int bh = idx >> 12;          // b*8+h
    const int ss = (idx >> 6) & 63;
    const int p  = idx & 63;
    KVT[((size_t)(bh * 64 + p)) * 64 + ss] = f2bf(s);
}

// =====================================================================
// LN + gate: y = Yattn + x*Dv -> LayerNorm(512) -> *g+b -> *z -> ybuf
// one wave per row, 8 channels/lane; no LDS, no barriers.
// =====================================================================
__global__ __launch_bounds__(256) void ln_gate_kernel(
    const bf16_t* __restrict__ Yattn, const bf16_t* __restrict__ xconv,
    const bf16_t* __restrict__ zx,
    const float* __restrict__ DA, const float* __restrict__ DB,
    const float* __restrict__ ln_g, const float* __restrict__ ln_b,
    bf16_t* __restrict__ ybuf)
{
    const int w = threadIdx.x >> 6, lane = threadIdx.x & 63;
    const int c0 = lane * 8;
    const int h = lane >> 3;
    float g[8], be[8];
    *(float4*)&g[0]  = *(const float4*)&ln_g[c0];
    *(float4*)&g[4]  = *(const float4*)&ln_g[c0 + 4];
    *(float4*)&be[0] = *(const float4*)&ln_b[c0];
    *(float4*)&be[4] = *(const float4*)&ln_b[c0 + 4];
    const int row0 = (blockIdx.x * 4 + w) * 4;

    for (int i = 0; i < 4; ++i) {
        const int row = row0 + i;
        const int b = row >> 13;
        const float Dv = (b < 2) ? DA[h] : DB[h];
        ushort8v yv = *(const ushort8v*)(Yattn + (size_t)row * DINNER + c0);
        ushort8v xv = *(const ushort8v*)(xconv + (size_t)row * CONVD + c0);
        float y[8];
        float s1 = 0.f, s2 = 0.f;
        #pragma unroll
        for (int q = 0; q < 8; ++q) {
            y[q] = bf2f(yv[q]) + bf2f(xv[q]) * Dv;
            s1 += y[q]; s2 += y[q] * y[q];
        }
        #pragma unroll
        for (int off = 32; off > 0; off >>= 1) {
            s1 += __shfl_xor(s1, off, 64);
            s2 += __shfl_xor(s2, off, 64);
        }
        const float mu = s1 * (1.f / 512.f);
        const float var = s2 * (1.f / 512.f) - mu * mu;
        const float rstd = rsqrtf(var + 1e-5f);
        ushort8v zv = *(const ushort8v*)(zx + (size_t)row * DPROJ + c0);
        ushort8v o;
        #pragma unroll
        for (int q = 0; q < 8; ++q)
            o[q] = f2bf(((y[q] - mu) * rstd * g[q] + be[q]) * bf2f(zv[q]));
        *(ushort8v*)(ybuf + (size_t)row * DINNER + c0) = o;
    }
}

// =====================================================================
extern "C" void kernel_launch(void* const* d_in, const int* in_sizes, int n_in,
                              void* d_out, int out_size, void* d_ws, size_t ws_size,
                              hipStream_t stream)
{
    const float* u        = (const float*)d_in[0];
    const float* W_in     = (const float*)d_in[3];
    const float* W_st     = (const float*)d_in[4];
    const float* conv_l_w = (const float*)d_in[5];
    const float* conv_l_b = (const float*)d_in[6];
    const float* conv_r_w = (const float*)d_in[7];
    const float* conv_r_b = (const float*)d_in[8];
    const float* conv_w   = (const float*)d_in[9];
    const float* conv_b   = (const float*)d_in[10];
    const float* dt_bias  = (const float*)d_in[11];
    const float* A_log    = (const float*)d_in[12];
    const float* D_l      = (const float*)d_in[13];
    const float* D_r      = (const float*)d_in[14];
    const float* Dp       = (const float*)d_in[15];
    const float* ln_g     = (const float*)d_in[16];
    const float* ln_b     = (const float*)d_in[17];
    const float* W_out    = (const float*)d_in[18];
    float* out = (float*)d_out;

    // ---- workspace layout: ~205 MB (KVp aliases ubf; KVT bf16; Yattn bf16) ----
    char* ws = (char*)d_ws;
    const size_t ZX_B    = (size_t)MROWS * DPROJ * 2;    //  76,021,760
    const size_t XCONV_B = (size_t)MROWS * CONVD * 2;    //  41,943,040
    const size_t YBUF_B  = (size_t)MROWS * DINNER * 2;   //  33,554,432
    const size_t DT_B    = (size_t)MROWS * NH * 4;       //   1,048,576
    const size_t KVT_B   = (size_t)NB * DINNER * 64 * 2; //     262,144
    const size_t UBF_B   = (size_t)MROWS * DMODEL * 2;   //  16,777,216 (== KVCH*131072*4)
    const size_t WIN_B   = (size_t)1280 * DMODEL * 2;
    const size_t WST_B   = (size_t)1280 * DINNER * 2;
    const size_t WOUT_B  = (size_t)256 * DINNER * 2;
    bf16_t* zx    = (bf16_t*)(ws);
    bf16_t* xconv = (bf16_t*)(ws + ZX_B);
    bf16_t* ybuf  = (bf16_t*)(ws + ZX_B + XCONV_B);
    float*  dtbuf = (float*) (ws + ZX_B + XCONV_B + YBUF_B);
    bf16_t* KVT   = (bf16_t*)(ws + ZX_B + XCONV_B + YBUF_B + DT_B);
    bf16_t* ubf   = (bf16_t*)(ws + ZX_B + XCONV_B + YBUF_B + DT_B + KVT_B);
    float*  KVp   = (float*) (ws + ZX_B + XCONV_B + YBUF_B + DT_B + KVT_B);  // alias (ubf dead after gemm1)
    bf16_t* WinP  = (bf16_t*)(ws + ZX_B + XCONV_B + YBUF_B + DT_B + KVT_B + UBF_B);
    bf16_t* WstP  = (bf16_t*)(ws + ZX_B + XCONV_B + YBUF_B + DT_B + KVT_B + UBF_B + WIN_B);
    bf16_t* WoutP = (bf16_t*)(ws + ZX_B + XCONV_B + YBUF_B + DT_B + KVT_B + UBF_B + WIN_B + WST_B);
    bf16_t* Yattn = (bf16_t*)(ws + ZX_B + XCONV_B + YBUF_B + DT_B + KVT_B + UBF_B + WIN_B + WST_B + WOUT_B);

    const dim3 gemmGridP(10, MROWS / 128);        // Npad=1280
    const dim3 gemmGridO(2,  MROWS / 128);        // N=256
    const dim3 ymmGrid(4, LSEQ / 128, NB);        // N=512, per-batch
    const dim3 kvGrid(KVCH, NH, NB);
    const int convGrid = MROWS * CBLK / 256;      // 10240
    const int lnGrid = MROWS / 16;                // 2048

    // ---- one-time conversions ----
    cvt_bf16_kernel<<<(MROWS * DMODEL / 4 + 255) / 256, 256, 0, stream>>>(u, ubf, MROWS * DMODEL);
    wpad_kernel<<<(1280 * DMODEL + 255) / 256, 256, 0, stream>>>(W_in, WinP, DPROJ, 1280, DMODEL);
    wpad_kernel<<<(1280 * DINNER + 255) / 256, 256, 0, stream>>>(W_st, WstP, DPROJ, 1280, DINNER);
    wpad_kernel<<<(256 * DINNER + 255) / 256, 256, 0, stream>>>(W_out, WoutP, DMODEL, 256, DINNER);

    // ---------------- pass 1 ----------------
    gemm_mfma_bt<bf16_t><<<gemmGridP, 256, 0, stream>>>(
        ubf, DMODEL, 0, WinP, DMODEL, 0, zx, DPROJ, 0, MROWS, DPROJ, DMODEL);
    dt_kernel<<<(MROWS * NH) / 256, 256, 0, stream>>>(zx, dt_bias, dtbuf);
    conv_silu_kernel<<<convGrid, 256, 0, stream>>>(
        zx, conv_l_w, conv_l_b, conv_r_w, conv_r_b, xconv);
    kv_part_kernel<<<kvGrid, 128, 0, stream>>>(xconv, dtbuf, A_log, KVp);
    kv_reduce_T_kernel<<<131072 / 256, 256, 0, stream>>>(KVp, KVT);
    gemm_mfma_bt<bf16_t><<<ymmGrid, 256, 0, stream>>>(
        xconv + DINNER + DSTATE, CONVD, (size_t)LSEQ * CONVD,
        KVT, 64, (size_t)DINNER * 64,
        Yattn, DINNER, (size_t)LSEQ * DINNER, LSEQ, DINNER, 64);
    ln_gate_kernel<<<lnGrid, 256, 0, stream>>>(
        Yattn, xconv, zx, D_l, D_r, ln_g, ln_b, ybuf);

    // ---------------- pass 2 ----------------
    gemm_mfma_bt<bf16_t><<<gemmGridP, 256, 0, stream>>>(
        ybuf, DINNER, 0, WstP, DINNER, 0, zx, DPROJ, 0, MROWS, DPROJ, DINNER);
    dt_kernel<<<(MROWS * NH) / 256, 256, 0, stream>>>(zx, dt_bias, dtbuf);
    conv_silu_kernel<<<convGrid, 256, 0, stream>>>(
        zx, conv_w, conv_b, conv_w, conv_b, xconv);
    kv_part_kernel<<<kvGrid, 128, 0, stream>>>(xconv, dtbuf, A_log, KVp);
    kv_reduce_T_kernel<<<131072 / 256, 256, 0, stream>>>(KVp, KVT);
    gemm_mfma_bt<bf16_t><<<ymmGrid, 256, 0, stream>>>(
        xconv + DINNER + DSTATE, CONVD, (size_t)LSEQ * CONVD,
        KVT, 64, (size_t)DINNER * 64,
        Yattn, DINNER, (size_t)LSEQ * DINNER, LSEQ, DINNER, 64);
    ln_gate_kernel<<<lnGrid, 256, 0, stream>>>(
        Yattn, xconv, zx, Dp, Dp, ln_g, ln_b, ybuf);

    // ---------------- output projection ----------------
    gemm_mfma_bt<float><<<gemmGridO, 256, 0, stream>>>(
        ybuf, DINNER, 0, WoutP, DINNER, 0, out, DMODEL, 0, MROWS, DMODEL, DINNER);
}

// Round 8
// 430.395 us; speedup vs baseline: 4.1496x; 1.0541x over previous
//
#include <hip/hip_runtime.h>
#include <hip/hip_bf16.h>
#include <math.h>

// ---- problem constants ----
#define NB    4          // batch
#define LSEQ  8192       // H*W
#define HH    64
#define WW    128
#define DMODEL 256
#define DINNER 512
#define NH    8          // heads
#define DSTATE 64
#define DPROJ 1160       // 2*512 + 2*64 + 8
#define CONVD 640        // 512 + 128
#define MROWS (NB*LSEQ)  // 32768
#define KVCH  32         // l-chunks per (b,h) in kv_part
#define CBLK  80         // 640/8 channel-blocks per position

typedef unsigned short bf16_t;
typedef __attribute__((ext_vector_type(8))) unsigned short ushort8v;
typedef __attribute__((ext_vector_type(8))) short short8v;   // MFMA A/B frag (8 bf16)
typedef __attribute__((ext_vector_type(4))) float f32x4;     // MFMA C/D frag

static __device__ __forceinline__ float bf2f(bf16_t u) {
    return __uint_as_float(((unsigned)u) << 16);
}
static __device__ __forceinline__ bf16_t f2bf(float f) {
    unsigned u = __float_as_uint(f);
    u += 0x7FFFu + ((u >> 16) & 1u);   // round-nearest-even
    return (bf16_t)(u >> 16);
}

// =====================================================================
// MFMA GEMM, BK=64 + LDS XOR-swizzle + XCD-chunked block swizzle.
// C[M,N] = A[M,K]bf16 @ B[Npad,K]bf16^T. M%128==0, K%64==0, grid %8==0.
// LDS rows are 128B; 16B slots are stored at slot = chunk ^ (row&7)
// (pre-swizzled GLOBAL source + swizzled ds_read: both-sides rule).
// =====================================================================
template <typename TC>
__global__ __launch_bounds__(256) void gemm_mfma_bk64(
    const bf16_t* __restrict__ A, int lda,
    const bf16_t* __restrict__ B, int ldb,
    TC* __restrict__ C, int ldc,
    int M, int N, int K)
{
    __shared__ __align__(16) bf16_t As[128 * 64];
    __shared__ __align__(16) bf16_t Bs[128 * 64];
    // --- XCD-aware bijective block swizzle (nwg % 8 == 0) ---
    const int nwg = gridDim.x * gridDim.y;
    const int wg  = blockIdx.y * gridDim.x + blockIdx.x;
    const int swz = (wg & 7) * (nwg >> 3) + (wg >> 3);
    const int bx  = swz % gridDim.x;
    const int by  = swz / gridDim.x;

    const int tid = threadIdx.x;
    const int m0 = by * 128;
    const int n0 = bx * 128;
    const int wid = tid >> 6;
    const int lane = tid & 63;
    const int wr = (wid >> 1) * 64;
    const int wc = (wid & 1) * 64;
    const int fr = lane & 15;
    const int kq = lane >> 4;        // 0..3

    f32x4 acc[4][4];
    #pragma unroll
    for (int i = 0; i < 4; ++i)
        #pragma unroll
        for (int j = 0; j < 4; ++j) acc[i][j] = (f32x4){0.f, 0.f, 0.f, 0.f};

    // staging geometry: 4 issues x 256 lanes x 16B covers 128x64 bf16
    const int lin0  = tid;                 // issue i uses lin = i*256+tid
    const int srow0 = lin0 >> 3;           // row advances by 32 per issue
    const int sslot = lin0 & 7;

    for (int k0 = 0; k0 < K; k0 += 64) {
        #pragma unroll
        for (int i = 0; i < 4; ++i) {
            const int row  = srow0 + i * 32;
            const int chunk = sslot ^ (row & 7);
            const size_t ga = (size_t)(m0 + row) * lda + k0 + chunk * 8;
            const size_t gb = (size_t)(n0 + row) * ldb + k0 + chunk * 8;
            const int ldst = (i * 256 + tid) * 8;
            __builtin_amdgcn_global_load_lds(
                (const __attribute__((address_space(1))) void*)(A + ga),
                (__attribute__((address_space(3))) void*)(As + ldst), 16, 0, 0);
            __builtin_amdgcn_global_load_lds(
                (const __attribute__((address_space(1))) void*)(B + gb),
                (__attribute__((address_space(3))) void*)(Bs + ldst), 16, 0, 0);
        }
        __syncthreads();   // compiler drains vmcnt before barrier

        short8v a_frag[2][4], b_frag[2][4];
        #pragma unroll
        for (int ks = 0; ks < 2; ++ks) {
            #pragma unroll
            for (int m = 0; m < 4; ++m) {
                const int row = wr + m * 16 + fr;
                const int slot = (ks * 4 + kq) ^ (fr & 7);
                a_frag[ks][m] = *(const short8v*)&As[row * 64 + slot * 8];
            }
            #pragma unroll
            for (int n = 0; n < 4; ++n) {
                const int row = wc + n * 16 + fr;
                const int slot = (ks * 4 + kq) ^ (fr & 7);
                b_frag[ks][n] = *(const short8v*)&Bs[row * 64 + slot * 8];
            }
        }
        #pragma unroll
        for (int ks = 0; ks < 2; ++ks)
            #pragma unroll
            for (int m = 0; m < 4; ++m)
                #pragma unroll
                for (int n = 0; n < 4; ++n)
                    acc[m][n] = __builtin_amdgcn_mfma_f32_16x16x32_bf16(
                        a_frag[ks][m], b_frag[ks][n], acc[m][n], 0, 0, 0);
        __syncthreads();
    }

    #pragma unroll
    for (int mi = 0; mi < 4; ++mi) {
        #pragma unroll
        for (int ni = 0; ni < 4; ++ni) {
            const int col = n0 + wc + ni * 16 + fr;
            if (col < N) {
                #pragma unroll
                for (int q = 0; q < 4; ++q) {
                    const int row = m0 + wr + mi * 16 + kq * 4 + q;
                    if constexpr (sizeof(TC) == 2)
                        C[(size_t)row * ldc + col] = f2bf(acc[mi][ni][q]);
                    else
                        C[(size_t)row * ldc + col] = acc[mi][ni][q];
                }
            }
        }
    }
}

// =====================================================================
// MFMA GEMM (m97 recipe, BK=32, batch strides) — used for ymm (K=64).
// =====================================================================
template <typename TC>
__global__ __launch_bounds__(256) void gemm_mfma_bt(
    const bf16_t* __restrict__ A, int lda, size_t sAb,
    const bf16_t* __restrict__ B, int ldb, size_t sBb,
    TC* __restrict__ C, int ldc, size_t sCb,
    int M, int N, int K)
{
    __shared__ __align__(16) bf16_t As[128 * 32];
    __shared__ __align__(16) bf16_t Bs[128 * 32];
    const bf16_t* Ab = A + blockIdx.z * sAb;
    const bf16_t* Bb = B + blockIdx.z * sBb;
    TC*            Cb = C + blockIdx.z * sCb;
    const int tid = threadIdx.x;
    const int m0 = blockIdx.y * 128;
    const int n0 = blockIdx.x * 128;
    const int wid = tid >> 6;
    const int lane = tid & 63;
    const int wr = (wid >> 1) * 64;
    const int wc = (wid & 1) * 64;
    const int fr = lane & 15;
    const int fk = (lane >> 4) * 8;

    f32x4 acc[4][4];
    #pragma unroll
    for (int i = 0; i < 4; ++i)
        #pragma unroll
        for (int j = 0; j < 4; ++j) acc[i][j] = (f32x4){0.f, 0.f, 0.f, 0.f};

    const int srow = tid >> 2;
    const int scol = (tid & 3) * 8;
    const bf16_t* gA = Ab + (size_t)(m0 + srow) * lda + scol;
    const bf16_t* gB = Bb + (size_t)(n0 + srow) * ldb + scol;
    bf16_t* lA = As + tid * 8;
    bf16_t* lB = Bs + tid * 8;

    for (int k0 = 0; k0 < K; k0 += 32) {
        __builtin_amdgcn_global_load_lds(
            (const __attribute__((address_space(1))) void*)(gA + k0),
            (__attribute__((address_space(3))) void*)lA, 16, 0, 0);
        __builtin_amdgcn_global_load_lds(
            (const __attribute__((address_space(1))) void*)(gA + (size_t)64 * lda + k0),
            (__attribute__((address_space(3))) void*)(lA + 2048), 16, 0, 0);
        __builtin_amdgcn_global_load_lds(
            (const __attribute__((address_space(1))) void*)(gB + k0),
            (__attribute__((address_space(3))) void*)lB, 16, 0, 0);
        __builtin_amdgcn_global_load_lds(
            (const __attribute__((address_space(1))) void*)(gB + (size_t)64 * ldb + k0),
            (__attribute__((address_space(3))) void*)(lB + 2048), 16, 0, 0);
        __syncthreads();

        short8v a_frag[4], b_frag[4];
        #pragma unroll
        for (int m = 0; m < 4; ++m)
            a_frag[m] = *(const short8v*)&As[(wr + m * 16 + fr) * 32 + fk];
        #pragma unroll
        for (int n = 0; n < 4; ++n)
            b_frag[n] = *(const short8v*)&Bs[(wc + n * 16 + fr) * 32 + fk];
        #pragma unroll
        for (int m = 0; m < 4; ++m)
            #pragma unroll
            for (int n = 0; n < 4; ++n)
                acc[m][n] = __builtin_amdgcn_mfma_f32_16x16x32_bf16(
                    a_frag[m], b_frag[n], acc[m][n], 0, 0, 0);
        __syncthreads();
    }

    #pragma unroll
    for (int mi = 0; mi < 4; ++mi) {
        #pragma unroll
        for (int ni = 0; ni < 4; ++ni) {
            const int col = n0 + wc + ni * 16 + fr;
            if (col < N) {
                #pragma unroll
                for (int q = 0; q < 4; ++q) {
                    const int row = m0 + wr + mi * 16 + (lane >> 4) * 4 + q;
                    if constexpr (sizeof(TC) == 2)
                        Cb[(size_t)row * ldc + col] = f2bf(acc[mi][ni][q]);
                    else
                        Cb[(size_t)row * ldc + col] = acc[mi][ni][q];
                }
            }
        }
    }
}

// =====================================================================
__global__ __launch_bounds__(256) void cvt_bf16_kernel(
    const float* __restrict__ in, bf16_t* __restrict__ out, int n)
{
    const int base = (blockIdx.x * 256 + threadIdx.x) * 4;
    if (base >= n) return;
    float4 v = *(const float4*)&in[base];
    ushort4 o;
    o.x = f2bf(v.x); o.y = f2bf(v.y); o.z = f2bf(v.z); o.w = f2bf(v.w);
    *(ushort4*)&out[base] = o;
}

__global__ __launch_bounds__(256) void wpad_kernel(
    const float* __restrict__ W, bf16_t* __restrict__ Wp,
    int N, int Npad, int K)
{
    const int i = blockIdx.x * 256 + threadIdx.x;
    if (i >= Npad * K) return;
    const int r = i / K, k = i - r * K;
    Wp[i] = (r < N) ? f2bf(W[(size_t)r * K + k]) : (bf16_t)0;
}

// =====================================================================
__global__ __launch_bounds__(256) void dt_kernel(
    const bf16_t* __restrict__ zx, const float* __restrict__ dt_bias,
    float* __restrict__ dtbuf)
{
    const int idx = blockIdx.x * 256 + threadIdx.x;   // < 32768*8
    const int h = idx & 7;
    const int row = idx >> 3;
    const float v = bf2f(zx[(size_t)row * DPROJ + (DINNER + CONVD) + h]) + dt_bias[h];
    const float sp = (v > 0.f) ? (v + log1pf(expf(-v))) : log1pf(expf(v));
    dtbuf[idx] = sp;
}

// =====================================================================
// 3x3 depthwise conv + bias + SiLU, channel-vectorized x8.
// =====================================================================
__global__ __launch_bounds__(256) void conv_silu_kernel(
    const bf16_t* __restrict__ zx,
    const float* __restrict__ wA, const float* __restrict__ bA,
    const float* __restrict__ wB, const float* __restrict__ bB,
    bf16_t* __restrict__ out)
{
    const int idx = blockIdx.x * 256 + threadIdx.x;   // < 32768*80
    const int cb = idx % CBLK;
    const int t  = idx / CBLK;
    const int c0 = cb * 8;
    const int l = t & (LSEQ - 1);
    const int b = t >> 13;
    const int hh = l >> 7;
    const int ww = l & (WW - 1);
    const float* wp = (b < 2) ? wA : wB;
    const float* bp = (b < 2) ? bA : bB;

    float w[72];
    const float4* wsrc = (const float4*)(wp + c0 * 9);
    #pragma unroll
    for (int i = 0; i < 18; ++i) ((float4*)w)[i] = wsrc[i];

    float acc[8];
    float4 bv0 = *(const float4*)(bp + c0);
    float4 bv1 = *(const float4*)(bp + c0 + 4);
    acc[0] = bv0.x; acc[1] = bv0.y; acc[2] = bv0.z; acc[3] = bv0.w;
    acc[4] = bv1.x; acc[5] = bv1.y; acc[6] = bv1.z; acc[7] = bv1.w;

    const bf16_t* base = zx + (size_t)b * LSEQ * DPROJ + DINNER + c0;
    #pragma unroll
    for (int ki = -1; ki <= 1; ++ki) {
        const int hi = hh + ki;
        if ((unsigned)hi >= (unsigned)HH) continue;
        #pragma unroll
        for (int kj = -1; kj <= 1; ++kj) {
            const int wi = ww + kj;
            if ((unsigned)wi >= (unsigned)WW) continue;
            const ushort8v v = *(const ushort8v*)(base + (size_t)(hi * WW + wi) * DPROJ);
            const int tap = (ki + 1) * 3 + (kj + 1);
            #pragma unroll
            for (int q = 0; q < 8; ++q) acc[q] += bf2f(v[q]) * w[q * 9 + tap];
        }
    }
    ushort8v o;
    #pragma unroll
    for (int q = 0; q < 8; ++q) {
        const float s = acc[q] / (1.f + expf(-acc[q]));   // silu
        o[q] = f2bf(s);
    }
    *(ushort8v*)(out + (size_t)t * CONVD + c0) = o;
}

// =====================================================================
// KV partials: KVp[chunk][(b*8+h)*4096 + s*64 + p]
// =====================================================================
__global__ __launch_bounds__(128) void kv_part_kernel(
    const bf16_t* __restrict__ xconv, const float* __restrict__ dtbuf,
    const float* __restrict__ A_log, float* __restrict__ KVp)
{
    const int h = blockIdx.y, b = blockIdx.z, chunk = blockIdx.x;
    const int tid = threadIdx.x;
    const int w = tid >> 6, lane = tid & 63;
    __shared__ float lds[2 * 4352];
    float* Bt = lds + w * 4352;
    float* Xt = Bt + 2176;
    const float eA = expf(A_log[h]);
    const int s4  = (lane & 15) * 4;
    const int p16 = (lane >> 4) * 16;
    const int r    = lane & 31;
    const int part = lane >> 5;

    float acc[4][16];
    #pragma unroll
    for (int i = 0; i < 4; ++i)
        #pragma unroll
        for (int j = 0; j < 16; ++j) acc[i][j] = 0.f;

    const int l0 = b * LSEQ + chunk * 256;

    for (int t = 0; t < 8; t += 2) {
        const int row = l0 + (t + w) * 32 + r;
        const bf16_t* src = xconv + (size_t)row * CONVD + (part ? h * 64 : DINNER);
        const float scale = part ? dtbuf[row * NH + h] * eA : 1.f;
        float* dst = part ? &Xt[r * 68] : &Bt[r * 68];
        #pragma unroll
        for (int j = 0; j < 8; ++j) {
            ushort8v v = *(const ushort8v*)(src + j * 8);
            f32x4 lo = {bf2f(v[0]) * scale, bf2f(v[1]) * scale,
                        bf2f(v[2]) * scale, bf2f(v[3]) * scale};
            f32x4 hi = {bf2f(v[4]) * scale, bf2f(v[5]) * scale,
                        bf2f(v[6]) * scale, bf2f(v[7]) * scale};
            *(f32x4*)&dst[j * 8]     = lo;
            *(f32x4*)&dst[j * 8 + 4] = hi;
        }
        __syncthreads();
        #pragma unroll 4
        for (int rr = 0; rr < 32; ++rr) {
            const f32x4 bv = *(const f32x4*)&Bt[rr * 68 + s4];
            #pragma unroll
            for (int q = 0; q < 4; ++q) {
                const f32x4 xv = *(const f32x4*)&Xt[rr * 68 + p16 + q * 4];
                #pragma unroll
                for (int si = 0; si < 4; ++si)
                    #pragma unroll
                    for (int k = 0; k < 4; ++k)
                        acc[si][q * 4 + k] += bv[si] * xv[k];
            }
        }
        __syncthreads();
    }

    if (w == 0) {
        #pragma unroll
        for (int si = 0; si < 4; ++si)
            #pragma unroll
            for (int q = 0; q < 4; ++q)
                *(f32x4*)&lds[(s4 + si) * 68 + p16 + q * 4] =
                    (f32x4){acc[si][q*4], acc[si][q*4+1], acc[si][q*4+2], acc[si][q*4+3]};
    }
    __syncthreads();
    if (w == 1) {
        float* dst = KVp + ((size_t)chunk * (NB * NH) + (b * NH + h)) * 4096;
        #pragma unroll
        for (int si = 0; si < 4; ++si)
            #pragma unroll
            for (int q = 0; q < 4; ++q) {
                const f32x4 o = *(const f32x4*)&lds[(s4 + si) * 68 + p16 + q * 4];
                f32x4 v = {acc[si][q*4] + o[0], acc[si][q*4+1] + o[1],
                           acc[si][q*4+2] + o[2], acc[si][q*4+3] + o[3]};
                *(f32x4*)&dst[(s4 + si) * 64 + p16 + q * 4] = v;
            }
    }
}

// =====================================================================
// KVT[b][h*64+p][s] (bf16) = sum_chunk KVp[chunk][(b*8+h)*4096+s*64+p]
// =====================================================================
__global__ __launch_bounds__(256) void kv_reduce_T_kernel(
    const float* __restrict__ KVp, bf16_t* __restrict__ KVT)
{
    const int idx = blockIdx.x * 256 + threadIdx.x;   // < 131072
    float s = 0.f;
    #pragma unroll
    for (int c = 0; c < KVCH; ++c) s += KVp[(size_t)c * 131072 + idx];
    const int bh = idx >> 12;          // b*8+h
    const int ss = (idx >> 6) & 63;
    const int p  = idx & 63;
    KVT[((size_t)(bh * 64 + p)) * 64 + ss] = f2bf(s);
}

// =====================================================================
// LN + gate: y = Yattn + x*Dv -> LayerNorm(512) -> *g+b -> *z -> ybuf
// =====================================================================
__global__ __launch_bounds__(256) void ln_gate_kernel(
    const bf16_t* __restrict__ Yattn, const bf16_t* __restrict__ xconv,
    const bf16_t* __restrict__ zx,
    const float* __restrict__ DA, const float* __restrict__ DB,
    const float* __restrict__ ln_g, const float* __restrict__ ln_b,
    bf16_t* __restrict__ ybuf)
{
    const int w = threadIdx.x >> 6, lane = threadIdx.x & 63;
    const int c0 = lane * 8;
    const int h = lane >> 3;
    float g[8], be[8];
    *(float4*)&g[0]  = *(const float4*)&ln_g[c0];
    *(float4*)&g[4]  = *(const float4*)&ln_g[c0 + 4];
    *(float4*)&be[0] = *(const float4*)&ln_b[c0];
    *(float4*)&be[4] = *(const float4*)&ln_b[c0 + 4];
    const int row0 = (blockIdx.x * 4 + w) * 4;

    for (int i = 0; i < 4; ++i) {
        const int row = row0 + i;
        const int b = row >> 13;
        const float Dv = (b < 2) ? DA[h] : DB[h];
        ushort8v yv = *(const ushort8v*)(Yattn + (size_t)row * DINNER + c0);
        ushort8v xv = *(const ushort8v*)(xconv + (size_t)row * CONVD + c0);
        float y[8];
        float s1 = 0.f, s2 = 0.f;
        #pragma unroll
        for (int q = 0; q < 8; ++q) {
            y[q] = bf2f(yv[q]) + bf2f(xv[q]) * Dv;
            s1 += y[q]; s2 += y[q] * y[q];
        }
        #pragma unroll
        for (int off = 32; off > 0; off >>= 1) {
            s1 += __shfl_xor(s1, off, 64);
            s2 += __shfl_xor(s2, off, 64);
        }
        const float mu = s1 * (1.f / 512.f);
        const float var = s2 * (1.f / 512.f) - mu * mu;
        const float rstd = rsqrtf(var + 1e-5f);
        ushort8v zv = *(const ushort8v*)(zx + (size_t)row * DPROJ + c0);
        ushort8v o;
        #pragma unroll
        for (int q = 0; q < 8; ++q)
            o[q] = f2bf(((y[q] - mu) * rstd * g[q] + be[q]) * bf2f(zv[q]));
        *(ushort8v*)(ybuf + (size_t)row * DINNER + c0) = o;
    }
}

// =====================================================================
extern "C" void kernel_launch(void* const* d_in, const int* in_sizes, int n_in,
                              void* d_out, int out_size, void* d_ws, size_t ws_size,
                              hipStream_t stream)
{
    const float* u        = (const float*)d_in[0];
    const float* W_in     = (const float*)d_in[3];
    const float* W_st     = (const float*)d_in[4];
    const float* conv_l_w = (const float*)d_in[5];
    const float* conv_l_b = (const float*)d_in[6];
    const float* conv_r_w = (const float*)d_in[7];
    const float* conv_r_b = (const float*)d_in[8];
    const float* conv_w   = (const float*)d_in[9];
    const float* conv_b   = (const float*)d_in[10];
    const float* dt_bias  = (const float*)d_in[11];
    const float* A_log    = (const float*)d_in[12];
    const float* D_l      = (const float*)d_in[13];
    const float* D_r      = (const float*)d_in[14];
    const float* Dp       = (const float*)d_in[15];
    const float* ln_g     = (const float*)d_in[16];
    const float* ln_b     = (const float*)d_in[17];
    const float* W_out    = (const float*)d_in[18];
    float* out = (float*)d_out;

    // ---- workspace layout: ~205 MB (KVp aliases ubf; KVT bf16; Yattn bf16) ----
    char* ws = (char*)d_ws;
    const size_t ZX_B    = (size_t)MROWS * DPROJ * 2;    //  76,021,760
    const size_t XCONV_B = (size_t)MROWS * CONVD * 2;    //  41,943,040
    const size_t YBUF_B  = (size_t)MROWS * DINNER * 2;   //  33,554,432
    const size_t DT_B    = (size_t)MROWS * NH * 4;       //   1,048,576
    const size_t KVT_B   = (size_t)NB * DINNER * 64 * 2; //     262,144
    const size_t UBF_B   = (size_t)MROWS * DMODEL * 2;   //  16,777,216 (== KVCH*131072*4)
    const size_t WIN_B   = (size_t)1280 * DMODEL * 2;
    const size_t WST_B   = (size_t)1280 * DINNER * 2;
    const size_t WOUT_B  = (size_t)256 * DINNER * 2;
    bf16_t* zx    = (bf16_t*)(ws);
    bf16_t* xconv = (bf16_t*)(ws + ZX_B);
    bf16_t* ybuf  = (bf16_t*)(ws + ZX_B + XCONV_B);
    float*  dtbuf = (float*) (ws + ZX_B + XCONV_B + YBUF_B);
    bf16_t* KVT   = (bf16_t*)(ws + ZX_B + XCONV_B + YBUF_B + DT_B);
    bf16_t* ubf   = (bf16_t*)(ws + ZX_B + XCONV_B + YBUF_B + DT_B + KVT_B);
    float*  KVp   = (float*) (ws + ZX_B + XCONV_B + YBUF_B + DT_B + KVT_B);  // alias (ubf dead after gemm1)
    bf16_t* WinP  = (bf16_t*)(ws + ZX_B + XCONV_B + YBUF_B + DT_B + KVT_B + UBF_B);
    bf16_t* WstP  = (bf16_t*)(ws + ZX_B + XCONV_B + YBUF_B + DT_B + KVT_B + UBF_B + WIN_B);
    bf16_t* WoutP = (bf16_t*)(ws + ZX_B + XCONV_B + YBUF_B + DT_B + KVT_B + UBF_B + WIN_B + WST_B);
    bf16_t* Yattn = (bf16_t*)(ws + ZX_B + XCONV_B + YBUF_B + DT_B + KVT_B + UBF_B + WIN_B + WST_B + WOUT_B);

    const dim3 gemmGridP(10, MROWS / 128);        // Npad=1280, 2560 blocks (%8==0)
    const dim3 gemmGridO(2,  MROWS / 128);        // N=256, 512 blocks (%8==0)
    const dim3 ymmGrid(4, LSEQ / 128, NB);        // N=512, per-batch
    const dim3 kvGrid(KVCH, NH, NB);
    const int convGrid = MROWS * CBLK / 256;      // 10240
    const int lnGrid = MROWS / 16;                // 2048

    // ---- one-time conversions ----
    cvt_bf16_kernel<<<(MROWS * DMODEL / 4 + 255) / 256, 256, 0, stream>>>(u, ubf, MROWS * DMODEL);
    wpad_kernel<<<(1280 * DMODEL + 255) / 256, 256, 0, stream>>>(W_in, WinP, DPROJ, 1280, DMODEL);
    wpad_kernel<<<(1280 * DINNER + 255) / 256, 256, 0, stream>>>(W_st, WstP, DPROJ, 1280, DINNER);
    wpad_kernel<<<(256 * DINNER + 255) / 256, 256, 0, stream>>>(W_out, WoutP, DMODEL, 256, DINNER);

    // ---------------- pass 1 ----------------
    gemm_mfma_bk64<bf16_t><<<gemmGridP, 256, 0, stream>>>(
        ubf, DMODEL, WinP, DMODEL, zx, DPROJ, MROWS, DPROJ, DMODEL);
    dt_kernel<<<(MROWS * NH) / 256, 256, 0, stream>>>(zx, dt_bias, dtbuf);
    conv_silu_kernel<<<convGrid, 256, 0, stream>>>(
        zx, conv_l_w, conv_l_b, conv_r_w, conv_r_b, xconv);
    kv_part_kernel<<<kvGrid, 128, 0, stream>>>(xconv, dtbuf, A_log, KVp);
    kv_reduce_T_kernel<<<131072 / 256, 256, 0, stream>>>(KVp, KVT);
    gemm_mfma_bt<bf16_t><<<ymmGrid, 256, 0, stream>>>(
        xconv + DINNER + DSTATE, CONVD, (size_t)LSEQ * CONVD,
        KVT, 64, (size_t)DINNER * 64,
        Yattn, DINNER, (size_t)LSEQ * DINNER, LSEQ, DINNER, 64);
    ln_gate_kernel<<<lnGrid, 256, 0, stream>>>(
        Yattn, xconv, zx, D_l, D_r, ln_g, ln_b, ybuf);

    // ---------------- pass 2 ----------------
    gemm_mfma_bk64<bf16_t><<<gemmGridP, 256, 0, stream>>>(
        ybuf, DINNER, WstP, DINNER, zx, DPROJ, MROWS, DPROJ, DINNER);
    dt_kernel<<<(MROWS * NH) / 256, 256, 0, stream>>>(zx, dt_bias, dtbuf);
    conv_silu_kernel<<<convGrid, 256, 0, stream>>>(
        zx, conv_w, conv_b, conv_w, conv_b, xconv);
    kv_part_kernel<<<kvGrid, 128, 0, stream>>>(xconv, dtbuf, A_log, KVp);
    kv_reduce_T_kernel<<<131072 / 256, 256, 0, stream>>>(KVp, KVT);
    gemm_mfma_bt<bf16_t><<<ymmGrid, 256, 0, stream>>>(
        xconv + DINNER + DSTATE, CONVD, (size_t)LSEQ * CONVD,
        KVT, 64, (size_t)DINNER * 64,
        Yattn, DINNER, (size_t)LSEQ * DINNER, LSEQ, DINNER, 64);
    ln_gate_kernel<<<lnGrid, 256, 0, stream>>>(
        Yattn, xconv, zx, Dp, Dp, ln_g, ln_b, ybuf);

    // ---------------- output projection ----------------
    gemm_mfma_bk64<float><<<gemmGridO, 256, 0, stream>>>(
        ybuf, DINNER, WoutP, DINNER, out, DMODEL, MROWS, DMODEL, DINNER);
}

// Round 9
// 387.335 us; speedup vs baseline: 4.6109x; 1.1112x over previous
//
#include <hip/hip_runtime.h>
#include <hip/hip_bf16.h>
#include <math.h>

// ---- problem constants ----
#define NB    4          // batch
#define LSEQ  8192       // H*W
#define HH    64
#define WW    128
#define DMODEL 256
#define DINNER 512
#define NH    8          // heads
#define DSTATE 64
#define DPROJ 1160       // 2*512 + 2*64 + 8
#define CONVD 640        // 512 + 128
#define MROWS (NB*LSEQ)  // 32768
#define KVCH  32         // l-chunks per (b,h) in kv_part
#define CBLK  80         // 640/8 channel-blocks per position

typedef unsigned short bf16_t;
typedef __attribute__((ext_vector_type(8))) unsigned short ushort8v;
typedef __attribute__((ext_vector_type(8))) short short8v;   // MFMA A/B frag (8 bf16)
typedef __attribute__((ext_vector_type(4))) float f32x4;     // MFMA C/D frag

static __device__ __forceinline__ float bf2f(bf16_t u) {
    return __uint_as_float(((unsigned)u) << 16);
}
static __device__ __forceinline__ bf16_t f2bf(float f) {
    unsigned u = __float_as_uint(f);
    u += 0x7FFFu + ((u >> 16) & 1u);   // round-nearest-even
    return (bf16_t)(u >> 16);
}

// =====================================================================
// MFMA GEMM, BK=64 + LDS XOR-swizzle + XCD-chunked block swizzle.
// =====================================================================
template <typename TC>
__global__ __launch_bounds__(256) void gemm_mfma_bk64(
    const bf16_t* __restrict__ A, int lda,
    const bf16_t* __restrict__ B, int ldb,
    TC* __restrict__ C, int ldc,
    int M, int N, int K)
{
    __shared__ __align__(16) bf16_t As[128 * 64];
    __shared__ __align__(16) bf16_t Bs[128 * 64];
    const int nwg = gridDim.x * gridDim.y;
    const int wg  = blockIdx.y * gridDim.x + blockIdx.x;
    const int swz = (wg & 7) * (nwg >> 3) + (wg >> 3);
    const int bx  = swz % gridDim.x;
    const int by  = swz / gridDim.x;

    const int tid = threadIdx.x;
    const int m0 = by * 128;
    const int n0 = bx * 128;
    const int wid = tid >> 6;
    const int lane = tid & 63;
    const int wr = (wid >> 1) * 64;
    const int wc = (wid & 1) * 64;
    const int fr = lane & 15;
    const int kq = lane >> 4;        // 0..3

    f32x4 acc[4][4];
    #pragma unroll
    for (int i = 0; i < 4; ++i)
        #pragma unroll
        for (int j = 0; j < 4; ++j) acc[i][j] = (f32x4){0.f, 0.f, 0.f, 0.f};

    const int lin0  = tid;
    const int srow0 = lin0 >> 3;
    const int sslot = lin0 & 7;

    for (int k0 = 0; k0 < K; k0 += 64) {
        #pragma unroll
        for (int i = 0; i < 4; ++i) {
            const int row  = srow0 + i * 32;
            const int chunk = sslot ^ (row & 7);
            const size_t ga = (size_t)(m0 + row) * lda + k0 + chunk * 8;
            const size_t gb = (size_t)(n0 + row) * ldb + k0 + chunk * 8;
            const int ldst = (i * 256 + tid) * 8;
            __builtin_amdgcn_global_load_lds(
                (const __attribute__((address_space(1))) void*)(A + ga),
                (__attribute__((address_space(3))) void*)(As + ldst), 16, 0, 0);
            __builtin_amdgcn_global_load_lds(
                (const __attribute__((address_space(1))) void*)(B + gb),
                (__attribute__((address_space(3))) void*)(Bs + ldst), 16, 0, 0);
        }
        __syncthreads();

        short8v a_frag[2][4], b_frag[2][4];
        #pragma unroll
        for (int ks = 0; ks < 2; ++ks) {
            #pragma unroll
            for (int m = 0; m < 4; ++m) {
                const int row = wr + m * 16 + fr;
                const int slot = (ks * 4 + kq) ^ (fr & 7);
                a_frag[ks][m] = *(const short8v*)&As[row * 64 + slot * 8];
            }
            #pragma unroll
            for (int n = 0; n < 4; ++n) {
                const int row = wc + n * 16 + fr;
                const int slot = (ks * 4 + kq) ^ (fr & 7);
                b_frag[ks][n] = *(const short8v*)&Bs[row * 64 + slot * 8];
            }
        }
        #pragma unroll
        for (int ks = 0; ks < 2; ++ks)
            #pragma unroll
            for (int m = 0; m < 4; ++m)
                #pragma unroll
                for (int n = 0; n < 4; ++n)
                    acc[m][n] = __builtin_amdgcn_mfma_f32_16x16x32_bf16(
                        a_frag[ks][m], b_frag[ks][n], acc[m][n], 0, 0, 0);
        __syncthreads();
    }

    #pragma unroll
    for (int mi = 0; mi < 4; ++mi) {
        #pragma unroll
        for (int ni = 0; ni < 4; ++ni) {
            const int col = n0 + wc + ni * 16 + fr;
            if (col < N) {
                #pragma unroll
                for (int q = 0; q < 4; ++q) {
                    const int row = m0 + wr + mi * 16 + kq * 4 + q;
                    if constexpr (sizeof(TC) == 2)
                        C[(size_t)row * ldc + col] = f2bf(acc[mi][ni][q]);
                    else
                        C[(size_t)row * ldc + col] = acc[mi][ni][q];
                }
            }
        }
    }
}

// =====================================================================
// MFMA GEMM (m97 recipe, BK=32, batch strides) — used for ymm (K=64).
// =====================================================================
template <typename TC>
__global__ __launch_bounds__(256) void gemm_mfma_bt(
    const bf16_t* __restrict__ A, int lda, size_t sAb,
    const bf16_t* __restrict__ B, int ldb, size_t sBb,
    TC* __restrict__ C, int ldc, size_t sCb,
    int M, int N, int K)
{
    __shared__ __align__(16) bf16_t As[128 * 32];
    __shared__ __align__(16) bf16_t Bs[128 * 32];
    const bf16_t* Ab = A + blockIdx.z * sAb;
    const bf16_t* Bb = B + blockIdx.z * sBb;
    TC*            Cb = C + blockIdx.z * sCb;
    const int tid = threadIdx.x;
    const int m0 = blockIdx.y * 128;
    const int n0 = blockIdx.x * 128;
    const int wid = tid >> 6;
    const int lane = tid & 63;
    const int wr = (wid >> 1) * 64;
    const int wc = (wid & 1) * 64;
    const int fr = lane & 15;
    const int fk = (lane >> 4) * 8;

    f32x4 acc[4][4];
    #pragma unroll
    for (int i = 0; i < 4; ++i)
        #pragma unroll
        for (int j = 0; j < 4; ++j) acc[i][j] = (f32x4){0.f, 0.f, 0.f, 0.f};

    const int srow = tid >> 2;
    const int scol = (tid & 3) * 8;
    const bf16_t* gA = Ab + (size_t)(m0 + srow) * lda + scol;
    const bf16_t* gB = Bb + (size_t)(n0 + srow) * ldb + scol;
    bf16_t* lA = As + tid * 8;
    bf16_t* lB = Bs + tid * 8;

    for (int k0 = 0; k0 < K; k0 += 32) {
        __builtin_amdgcn_global_load_lds(
            (const __attribute__((address_space(1))) void*)(gA + k0),
            (__attribute__((address_space(3))) void*)lA, 16, 0, 0);
        __builtin_amdgcn_global_load_lds(
            (const __attribute__((address_space(1))) void*)(gA + (size_t)64 * lda + k0),
            (__attribute__((address_space(3))) void*)(lA + 2048), 16, 0, 0);
        __builtin_amdgcn_global_load_lds(
            (const __attribute__((address_space(1))) void*)(gB + k0),
            (__attribute__((address_space(3))) void*)lB, 16, 0, 0);
        __builtin_amdgcn_global_load_lds(
            (const __attribute__((address_space(1))) void*)(gB + (size_t)64 * ldb + k0),
            (__attribute__((address_space(3))) void*)(lB + 2048), 16, 0, 0);
        __syncthreads();

        short8v a_frag[4], b_frag[4];
        #pragma unroll
        for (int m = 0; m < 4; ++m)
            a_frag[m] = *(const short8v*)&As[(wr + m * 16 + fr) * 32 + fk];
        #pragma unroll
        for (int n = 0; n < 4; ++n)
            b_frag[n] = *(const short8v*)&Bs[(wc + n * 16 + fr) * 32 + fk];
        #pragma unroll
        for (int m = 0; m < 4; ++m)
            #pragma unroll
            for (int n = 0; n < 4; ++n)
                acc[m][n] = __builtin_amdgcn_mfma_f32_16x16x32_bf16(
                    a_frag[m], b_frag[n], acc[m][n], 0, 0, 0);
        __syncthreads();
    }

    #pragma unroll
    for (int mi = 0; mi < 4; ++mi) {
        #pragma unroll
        for (int ni = 0; ni < 4; ++ni) {
            const int col = n0 + wc + ni * 16 + fr;
            if (col < N) {
                #pragma unroll
                for (int q = 0; q < 4; ++q) {
                    const int row = m0 + wr + mi * 16 + (lane >> 4) * 4 + q;
                    if constexpr (sizeof(TC) == 2)
                        Cb[(size_t)row * ldc + col] = f2bf(acc[mi][ni][q]);
                    else
                        Cb[(size_t)row * ldc + col] = acc[mi][ni][q];
                }
            }
        }
    }
}

// =====================================================================
__global__ __launch_bounds__(256) void cvt_bf16_kernel(
    const float* __restrict__ in, bf16_t* __restrict__ out, int n)
{
    const int base = (blockIdx.x * 256 + threadIdx.x) * 4;
    if (base >= n) return;
    float4 v = *(const float4*)&in[base];
    ushort4 o;
    o.x = f2bf(v.x); o.y = f2bf(v.y); o.z = f2bf(v.z); o.w = f2bf(v.w);
    *(ushort4*)&out[base] = o;
}

__global__ __launch_bounds__(256) void wpad_kernel(
    const float* __restrict__ W, bf16_t* __restrict__ Wp,
    int N, int Npad, int K)
{
    const int i = blockIdx.x * 256 + threadIdx.x;
    if (i >= Npad * K) return;
    const int r = i / K, k = i - r * K;
    Wp[i] = (r < N) ? f2bf(W[(size_t)r * K + k]) : (bf16_t)0;
}

// =====================================================================
__global__ __launch_bounds__(256) void dt_kernel(
    const bf16_t* __restrict__ zx, const float* __restrict__ dt_bias,
    float* __restrict__ dtbuf)
{
    const int idx = blockIdx.x * 256 + threadIdx.x;   // < 32768*8
    const int h = idx & 7;
    const int row = idx >> 3;
    const float v = bf2f(zx[(size_t)row * DPROJ + (DINNER + CONVD) + h]) + dt_bias[h];
    const float sp = (v > 0.f) ? (v + log1pf(expf(-v))) : log1pf(expf(v));
    dtbuf[idx] = sp;
}

// =====================================================================
// 3x3 depthwise conv + bias + SiLU, channel-vectorized x8,
// 4 vertically-stacked outputs per thread (weights amortized 4x).
// thread = (b, h4, w, cb): outputs rows h4*4..h4*4+3 at column w,
// channels cb*8..cb*8+7. Streaming 6-row window, 18 input loads.
// =====================================================================
__global__ __launch_bounds__(256) void conv_silu_kernel(
    const bf16_t* __restrict__ zx,
    const float* __restrict__ wA, const float* __restrict__ bA,
    const float* __restrict__ wB, const float* __restrict__ bB,
    bf16_t* __restrict__ out)
{
    const int idx = blockIdx.x * 256 + threadIdx.x;   // < 8192*80
    const int cb = idx % CBLK;
    const int pc = idx / CBLK;         // (b,h4,w) column id, < 8192
    const int c0 = cb * 8;
    const int ww = pc & (WW - 1);
    const int h4 = (pc >> 7) & 15;
    const int b  = pc >> 11;
    const int hbase = h4 * 4;
    const float* wp = (b < 2) ? wA : wB;
    const float* bp = (b < 2) ? bA : bB;

    // 8 channels x 9 taps of weights -> registers (18 x float4)
    float w[72];
    const float4* wsrc = (const float4*)(wp + c0 * 9);
    #pragma unroll
    for (int i = 0; i < 18; ++i) ((float4*)w)[i] = wsrc[i];

    float acc[4][8];
    {
        float4 bv0 = *(const float4*)(bp + c0);
        float4 bv1 = *(const float4*)(bp + c0 + 4);
        #pragma unroll
        for (int o = 0; o < 4; ++o) {
            acc[o][0] = bv0.x; acc[o][1] = bv0.y; acc[o][2] = bv0.z; acc[o][3] = bv0.w;
            acc[o][4] = bv1.x; acc[o][5] = bv1.y; acc[o][6] = bv1.z; acc[o][7] = bv1.w;
        }
    }

    const bf16_t* base = zx + (size_t)b * LSEQ * DPROJ + DINNER + c0;
    #pragma unroll
    for (int ri = 0; ri < 6; ++ri) {           // input rows hbase-1 .. hbase+4
        const int hi = hbase + ri - 1;
        const bool hok = (unsigned)hi < (unsigned)HH;
        float cur[3][8];
        #pragma unroll
        for (int kj = 0; kj < 3; ++kj) {
            const int wi = ww + kj - 1;
            if (hok && (unsigned)wi < (unsigned)WW) {
                const ushort8v v = *(const ushort8v*)(base + (size_t)(hi * WW + wi) * DPROJ);
                #pragma unroll
                for (int q = 0; q < 8; ++q) cur[kj][q] = bf2f(v[q]);
            } else {
                #pragma unroll
                for (int q = 0; q < 8; ++q) cur[kj][q] = 0.f;
            }
        }
        #pragma unroll
        for (int o = 0; o < 4; ++o) {
            const int ki = ri - o;             // tap row for output o
            if (ki >= 0 && ki < 3) {
                #pragma unroll
                for (int kj = 0; kj < 3; ++kj)
                    #pragma unroll
                    for (int q = 0; q < 8; ++q)
                        acc[o][q] += cur[kj][q] * w[q * 9 + ki * 3 + kj];
            }
        }
    }

    #pragma unroll
    for (int o = 0; o < 4; ++o) {
        const int t = b * LSEQ + (hbase + o) * WW + ww;
        ushort8v ov;
        #pragma unroll
        for (int q = 0; q < 8; ++q) {
            const float s = acc[o][q] / (1.f + expf(-acc[o][q]));   // silu
            ov[q] = f2bf(s);
        }
        *(ushort8v*)(out + (size_t)t * CONVD + c0) = ov;
    }
}

// =====================================================================
// KV partials: KVp[chunk][(b*8+h)*4096 + s*64 + p]
// =====================================================================
__global__ __launch_bounds__(128) void kv_part_kernel(
    const bf16_t* __restrict__ xconv, const float* __restrict__ dtbuf,
    const float* __restrict__ A_log, float* __restrict__ KVp)
{
    const int h = blockIdx.y, b = blockIdx.z, chunk = blockIdx.x;
    const int tid = threadIdx.x;
    const int w = tid >> 6, lane = tid & 63;
    __shared__ float lds[2 * 4352];
    float* Bt = lds + w * 4352;
    float* Xt = Bt + 2176;
    const float eA = expf(A_log[h]);
    const int s4  = (lane & 15) * 4;
    const int p16 = (lane >> 4) * 16;
    const int r    = lane & 31;
    const int part = lane >> 5;

    float acc[4][16];
    #pragma unroll
    for (int i = 0; i < 4; ++i)
        #pragma unroll
        for (int j = 0; j < 16; ++j) acc[i][j] = 0.f;

    const int l0 = b * LSEQ + chunk * 256;

    for (int t = 0; t < 8; t += 2) {
        const int row = l0 + (t + w) * 32 + r;
        const bf16_t* src = xconv + (size_t)row * CONVD + (part ? h * 64 : DINNER);
        const float scale = part ? dtbuf[row * NH + h] * eA : 1.f;
        float* dst = part ? &Xt[r * 68] : &Bt[r * 68];
        #pragma unroll
        for (int j = 0; j < 8; ++j) {
            ushort8v v = *(const ushort8v*)(src + j * 8);
            f32x4 lo = {bf2f(v[0]) * scale, bf2f(v[1]) * scale,
                        bf2f(v[2]) * scale, bf2f(v[3]) * scale};
            f32x4 hi = {bf2f(v[4]) * scale, bf2f(v[5]) * scale,
                        bf2f(v[6]) * scale, bf2f(v[7]) * scale};
            *(f32x4*)&dst[j * 8]     = lo;
            *(f32x4*)&dst[j * 8 + 4] = hi;
        }
        __syncthreads();
        #pragma unroll 4
        for (int rr = 0; rr < 32; ++rr) {
            const f32x4 bv = *(const f32x4*)&Bt[rr * 68 + s4];
            #pragma unroll
            for (int q = 0; q < 4; ++q) {
                const f32x4 xv = *(const f32x4*)&Xt[rr * 68 + p16 + q * 4];
                #pragma unroll
                for (int si = 0; si < 4; ++si)
                    #pragma unroll
                    for (int k = 0; k < 4; ++k)
                        acc[si][q * 4 + k] += bv[si] * xv[k];
            }
        }
        __syncthreads();
    }

    if (w == 0) {
        #pragma unroll
        for (int si = 0; si < 4; ++si)
            #pragma unroll
            for (int q = 0; q < 4; ++q)
                *(f32x4*)&lds[(s4 + si) * 68 + p16 + q * 4] =
                    (f32x4){acc[si][q*4], acc[si][q*4+1], acc[si][q*4+2], acc[si][q*4+3]};
    }
    __syncthreads();
    if (w == 1) {
        float* dst = KVp + ((size_t)chunk * (NB * NH) + (b * NH + h)) * 4096;
        #pragma unroll
        for (int si = 0; si < 4; ++si)
            #pragma unroll
            for (int q = 0; q < 4; ++q) {
                const f32x4 o = *(const f32x4*)&lds[(s4 + si) * 68 + p16 + q * 4];
                f32x4 v = {acc[si][q*4] + o[0], acc[si][q*4+1] + o[1],
                           acc[si][q*4+2] + o[2], acc[si][q*4+3] + o[3]};
                *(f32x4*)&dst[(s4 + si) * 64 + p16 + q * 4] = v;
            }
    }
}

// =====================================================================
// KVT[b][h*64+p][s] (bf16) = sum_chunk KVp[chunk][(b*8+h)*4096+s*64+p]
// =====================================================================
__global__ __launch_bounds__(256) void kv_reduce_T_kernel(
    const float* __restrict__ KVp, bf16_t* __restrict__ KVT)
{
    const int idx = blockIdx.x * 256 + threadIdx.x;   // < 131072
    float s = 0.f;
    #pragma unroll
    for (int c = 0; c < KVCH; ++c) s += KVp[(size_t)c * 131072 + idx];
    const int bh = idx >> 12;          // b*8+h
    const int ss = (idx >> 6) & 63;
    const int p  = idx & 63;
    KVT[((size_t)(bh * 64 + p)) * 64 + ss] = f2bf(s);
}

// =====================================================================
// LN + gate: y = Yattn + x*Dv -> LayerNorm(512) -> *g+b -> *z -> ybuf
// =====================================================================
__global__ __launch_bounds__(256) void ln_gate_kernel(
    const bf16_t* __restrict__ Yattn, const bf16_t* __restrict__ xconv,
    const bf16_t* __restrict__ zx,
    const float* __restrict__ DA, const float* __restrict__ DB,
    const float* __restrict__ ln_g, const float* __restrict__ ln_b,
    bf16_t* __restrict__ ybuf)
{
    const int w = threadIdx.x >> 6, lane = threadIdx.x & 63;
    const int c0 = lane * 8;
    const int h = lane >> 3;
    float g[8], be[8];
    *(float4*)&g[0]  = *(const float4*)&ln_g[c0];
    *(float4*)&g[4]  = *(const float4*)&ln_g[c0 + 4];
    *(float4*)&be[0] = *(const float4*)&ln_b[c0];
    *(float4*)&be[4] = *(const float4*)&ln_b[c0 + 4];
    const int row0 = (blockIdx.x * 4 + w) * 4;

    for (int i = 0; i < 4; ++i) {
        const int row = row0 + i;
        const int b = row >> 13;
        const float Dv = (b < 2) ? DA[h] : DB[h];
        ushort8v yv = *(const ushort8v*)(Yattn + (size_t)row * DINNER + c0);
        ushort8v xv = *(const ushort8v*)(xconv + (size_t)row * CONVD + c0);
        float y[8];
        float s1 = 0.f, s2 = 0.f;
        #pragma unroll
        for (int q = 0; q < 8; ++q) {
            y[q] = bf2f(yv[q]) + bf2f(xv[q]) * Dv;
            s1 += y[q]; s2 += y[q] * y[q];
        }
        #pragma unroll
        for (int off = 32; off > 0; off >>= 1) {
            s1 += __shfl_xor(s1, off, 64);
            s2 += __shfl_xor(s2, off, 64);
        }
        const float mu = s1 * (1.f / 512.f);
        const float var = s2 * (1.f / 512.f) - mu * mu;
        const float rstd = rsqrtf(var + 1e-5f);
        ushort8v zv = *(const ushort8v*)(zx + (size_t)row * DPROJ + c0);
        ushort8v o;
        #pragma unroll
        for (int q = 0; q < 8; ++q)
            o[q] = f2bf(((y[q] - mu) * rstd * g[q] + be[q]) * bf2f(zv[q]));
        *(ushort8v*)(ybuf + (size_t)row * DINNER + c0) = o;
    }
}

// =====================================================================
extern "C" void kernel_launch(void* const* d_in, const int* in_sizes, int n_in,
                              void* d_out, int out_size, void* d_ws, size_t ws_size,
                              hipStream_t stream)
{
    const float* u        = (const float*)d_in[0];
    const float* W_in     = (const float*)d_in[3];
    const float* W_st     = (const float*)d_in[4];
    const float* conv_l_w = (const float*)d_in[5];
    const float* conv_l_b = (const float*)d_in[6];
    const float* conv_r_w = (const float*)d_in[7];
    const float* conv_r_b = (const float*)d_in[8];
    const float* conv_w   = (const float*)d_in[9];
    const float* conv_b   = (const float*)d_in[10];
    const float* dt_bias  = (const float*)d_in[11];
    const float* A_log    = (const float*)d_in[12];
    const float* D_l      = (const float*)d_in[13];
    const float* D_r      = (const float*)d_in[14];
    const float* Dp       = (const float*)d_in[15];
    const float* ln_g     = (const float*)d_in[16];
    const float* ln_b     = (const float*)d_in[17];
    const float* W_out    = (const float*)d_in[18];
    float* out = (float*)d_out;

    // ---- workspace layout: ~205 MB (KVp aliases ubf; KVT bf16; Yattn bf16) ----
    char* ws = (char*)d_ws;
    const size_t ZX_B    = (size_t)MROWS * DPROJ * 2;    //  76,021,760
    const size_t XCONV_B = (size_t)MROWS * CONVD * 2;    //  41,943,040
    const size_t YBUF_B  = (size_t)MROWS * DINNER * 2;   //  33,554,432
    const size_t DT_B    = (size_t)MROWS * NH * 4;       //   1,048,576
    const size_t KVT_B   = (size_t)NB * DINNER * 64 * 2; //     262,144
    const size_t UBF_B   = (size_t)MROWS * DMODEL * 2;   //  16,777,216 (== KVCH*131072*4)
    const size_t WIN_B   = (size_t)1280 * DMODEL * 2;
    const size_t WST_B   = (size_t)1280 * DINNER * 2;
    const size_t WOUT_B  = (size_t)256 * DINNER * 2;
    bf16_t* zx    = (bf16_t*)(ws);
    bf16_t* xconv = (bf16_t*)(ws + ZX_B);
    bf16_t* ybuf  = (bf16_t*)(ws + ZX_B + XCONV_B);
    float*  dtbuf = (float*) (ws + ZX_B + XCONV_B + YBUF_B);
    bf16_t* KVT   = (bf16_t*)(ws + ZX_B + XCONV_B + YBUF_B + DT_B);
    bf16_t* ubf   = (bf16_t*)(ws + ZX_B + XCONV_B + YBUF_B + DT_B + KVT_B);
    float*  KVp   = (float*) (ws + ZX_B + XCONV_B + YBUF_B + DT_B + KVT_B);  // alias (ubf dead after gemm1)
    bf16_t* WinP  = (bf16_t*)(ws + ZX_B + XCONV_B + YBUF_B + DT_B + KVT_B + UBF_B);
    bf16_t* WstP  = (bf16_t*)(ws + ZX_B + XCONV_B + YBUF_B + DT_B + KVT_B + UBF_B + WIN_B);
    bf16_t* WoutP = (bf16_t*)(ws + ZX_B + XCONV_B + YBUF_B + DT_B + KVT_B + UBF_B + WIN_B + WST_B);
    bf16_t* Yattn = (bf16_t*)(ws + ZX_B + XCONV_B + YBUF_B + DT_B + KVT_B + UBF_B + WIN_B + WST_B + WOUT_B);

    const dim3 gemmGridP(10, MROWS / 128);        // Npad=1280, 2560 blocks (%8==0)
    const dim3 gemmGridO(2,  MROWS / 128);        // N=256, 512 blocks (%8==0)
    const dim3 ymmGrid(4, LSEQ / 128, NB);        // N=512, per-batch
    const dim3 kvGrid(KVCH, NH, NB);
    const int convGrid = (MROWS / 4) * CBLK / 256; // 2560
    const int lnGrid = MROWS / 16;                 // 2048

    // ---- one-time conversions ----
    cvt_bf16_kernel<<<(MROWS * DMODEL / 4 + 255) / 256, 256, 0, stream>>>(u, ubf, MROWS * DMODEL);
    wpad_kernel<<<(1280 * DMODEL + 255) / 256, 256, 0, stream>>>(W_in, WinP, DPROJ, 1280, DMODEL);
    wpad_kernel<<<(1280 * DINNER + 255) / 256, 256, 0, stream>>>(W_st, WstP, DPROJ, 1280, DINNER);
    wpad_kernel<<<(256 * DINNER + 255) / 256, 256, 0, stream>>>(W_out, WoutP, DMODEL, 256, DINNER);

    // ---------------- pass 1 ----------------
    gemm_mfma_bk64<bf16_t><<<gemmGridP, 256, 0, stream>>>(
        ubf, DMODEL, WinP, DMODEL, zx, DPROJ, MROWS, DPROJ, DMODEL);
    dt_kernel<<<(MROWS * NH) / 256, 256, 0, stream>>>(zx, dt_bias, dtbuf);
    conv_silu_kernel<<<convGrid, 256, 0, stream>>>(
        zx, conv_l_w, conv_l_b, conv_r_w, conv_r_b, xconv);
    kv_part_kernel<<<kvGrid, 128, 0, stream>>>(xconv, dtbuf, A_log, KVp);
    kv_reduce_T_kernel<<<131072 / 256, 256, 0, stream>>>(KVp, KVT);
    gemm_mfma_bt<bf16_t><<<ymmGrid, 256, 0, stream>>>(
        xconv + DINNER + DSTATE, CONVD, (size_t)LSEQ * CONVD,
        KVT, 64, (size_t)DINNER * 64,
        Yattn, DINNER, (size_t)LSEQ * DINNER, LSEQ, DINNER, 64);
    ln_gate_kernel<<<lnGrid, 256, 0, stream>>>(
        Yattn, xconv, zx, D_l, D_r, ln_g, ln_b, ybuf);

    // ---------------- pass 2 ----------------
    gemm_mfma_bk64<bf16_t><<<gemmGridP, 256, 0, stream>>>(
        ybuf, DINNER, WstP, DINNER, zx, DPROJ, MROWS, DPROJ, DINNER);
    dt_kernel<<<(MROWS * NH) / 256, 256, 0, stream>>>(zx, dt_bias, dtbuf);
    conv_silu_kernel<<<convGrid, 256, 0, stream>>>(
        zx, conv_w, conv_b, conv_w, conv_b, xconv);
    kv_part_kernel<<<kvGrid, 128, 0, stream>>>(xconv, dtbuf, A_log, KVp);
    kv_reduce_T_kernel<<<131072 / 256, 256, 0, stream>>>(KVp, KVT);
    gemm_mfma_bt<bf16_t><<<ymmGrid, 256, 0, stream>>>(
        xconv + DINNER + DSTATE, CONVD, (size_t)LSEQ * CONVD,
        KVT, 64, (size_t)DINNER * 64,
        Yattn, DINNER, (size_t)LSEQ * DINNER, LSEQ, DINNER, 64);
    ln_gate_kernel<<<lnGrid, 256, 0, stream>>>(
        Yattn, xconv, zx, Dp, Dp, ln_g, ln_b, ybuf);

    // ---------------- output projection ----------------
    gemm_mfma_bk64<float><<<gemmGridO, 256, 0, stream>>>(
        ybuf, DINNER, WoutP, DINNER, out, DMODEL, MROWS, DMODEL, DINNER);
}

// Round 10
// 382.310 us; speedup vs baseline: 4.6715x; 1.0131x over previous
//
#include <hip/hip_runtime.h>
#include <hip/hip_bf16.h>
#include <math.h>

// ---- problem constants ----
#define NB    4          // batch
#define LSEQ  8192       // H*W
#define HH    64
#define WW    128
#define DMODEL 256
#define DINNER 512
#define NH    8          // heads
#define DSTATE 64
#define DPROJ 1160       // 2*512 + 2*64 + 8
#define CONVD 640        // 512 + 128
#define MROWS (NB*LSEQ)  // 32768
#define KVCH  32         // l-chunks per (b,h) in kv_part
#define CBLK  80         // 640/8 channel-blocks per position

typedef unsigned short bf16_t;
typedef __attribute__((ext_vector_type(8))) unsigned short ushort8v;
typedef __attribute__((ext_vector_type(8))) short short8v;   // MFMA A/B frag (8 bf16)
typedef __attribute__((ext_vector_type(4))) float f32x4;     // MFMA C/D frag

static __device__ __forceinline__ float bf2f(bf16_t u) {
    return __uint_as_float(((unsigned)u) << 16);
}
static __device__ __forceinline__ bf16_t f2bf(float f) {
    unsigned u = __float_as_uint(f);
    u += 0x7FFFu + ((u >> 16) & 1u);   // round-nearest-even
    return (bf16_t)(u >> 16);
}

// =====================================================================
// MFMA GEMM, BK=64, 2-phase double-buffered LDS (T3 minimum recipe):
// per iter: STAGE(t+1 -> buf^1) BEFORE compute(t from buf); ONE barrier.
// LDS XOR-swizzle both-sides (pre-swizzled global src + swizzled read);
// XCD-chunked bijective block swizzle (grid %8==0). M%128, K%64.
// =====================================================================
template <typename TC>
__global__ __launch_bounds__(256) void gemm_mfma_bk64(
    const bf16_t* __restrict__ A, int lda,
    const bf16_t* __restrict__ B, int ldb,
    TC* __restrict__ C, int ldc,
    int M, int N, int K)
{
    __shared__ __align__(16) bf16_t As[2][128 * 64];
    __shared__ __align__(16) bf16_t Bs[2][128 * 64];
    const int nwg = gridDim.x * gridDim.y;
    const int wg  = blockIdx.y * gridDim.x + blockIdx.x;
    const int swz = (wg & 7) * (nwg >> 3) + (wg >> 3);
    const int bx  = swz % gridDim.x;
    const int by  = swz / gridDim.x;

    const int tid = threadIdx.x;
    const int m0 = by * 128;
    const int n0 = bx * 128;
    const int wid = tid >> 6;
    const int lane = tid & 63;
    const int wr = (wid >> 1) * 64;
    const int wc = (wid & 1) * 64;
    const int fr = lane & 15;
    const int kq = lane >> 4;        // 0..3

    f32x4 acc[4][4];
    #pragma unroll
    for (int i = 0; i < 4; ++i)
        #pragma unroll
        for (int j = 0; j < 4; ++j) acc[i][j] = (f32x4){0.f, 0.f, 0.f, 0.f};

    const int srow0 = tid >> 3;
    const int sslot = tid & 7;

    // staging: 4 issues x 256 lanes x 16B covers one 128x64 bf16 tile each of A,B
#define STAGE_BK64(buf, k0)                                                    \
    {                                                                          \
        _Pragma("unroll")                                                      \
        for (int i = 0; i < 4; ++i) {                                          \
            const int row  = srow0 + i * 32;                                   \
            const int chunk = sslot ^ (row & 7);                               \
            const size_t ga = (size_t)(m0 + row) * lda + (k0) + chunk * 8;     \
            const size_t gb = (size_t)(n0 + row) * ldb + (k0) + chunk * 8;     \
            const int ldst = (i * 256 + tid) * 8;                              \
            __builtin_amdgcn_global_load_lds(                                  \
                (const __attribute__((address_space(1))) void*)(A + ga),       \
                (__attribute__((address_space(3))) void*)(&As[buf][ldst]), 16, 0, 0); \
            __builtin_amdgcn_global_load_lds(                                  \
                (const __attribute__((address_space(1))) void*)(B + gb),       \
                (__attribute__((address_space(3))) void*)(&Bs[buf][ldst]), 16, 0, 0); \
        }                                                                      \
    }

    const int nt = K >> 6;
    STAGE_BK64(0, 0);
    __syncthreads();                       // drain prologue staging

    int cur = 0;
    for (int t = 0; t < nt; ++t) {
        if (t + 1 < nt) STAGE_BK64(cur ^ 1, (t + 1) * 64);   // prefetch next tile

        short8v a_frag[2][4], b_frag[2][4];
        #pragma unroll
        for (int ks = 0; ks < 2; ++ks) {
            #pragma unroll
            for (int m = 0; m < 4; ++m) {
                const int row = wr + m * 16 + fr;
                const int slot = (ks * 4 + kq) ^ (fr & 7);
                a_frag[ks][m] = *(const short8v*)&As[cur][row * 64 + slot * 8];
            }
            #pragma unroll
            for (int n = 0; n < 4; ++n) {
                const int row = wc + n * 16 + fr;
                const int slot = (ks * 4 + kq) ^ (fr & 7);
                b_frag[ks][n] = *(const short8v*)&Bs[cur][row * 64 + slot * 8];
            }
        }
        #pragma unroll
        for (int ks = 0; ks < 2; ++ks)
            #pragma unroll
            for (int m = 0; m < 4; ++m)
                #pragma unroll
                for (int n = 0; n < 4; ++n)
                    acc[m][n] = __builtin_amdgcn_mfma_f32_16x16x32_bf16(
                        a_frag[ks][m], b_frag[ks][n], acc[m][n], 0, 0, 0);

        __syncthreads();   // drains prefetch vmcnt + guards buffer reuse
        cur ^= 1;
    }
#undef STAGE_BK64

    #pragma unroll
    for (int mi = 0; mi < 4; ++mi) {
        #pragma unroll
        for (int ni = 0; ni < 4; ++ni) {
            const int col = n0 + wc + ni * 16 + fr;
            if (col < N) {
                #pragma unroll
                for (int q = 0; q < 4; ++q) {
                    const int row = m0 + wr + mi * 16 + kq * 4 + q;
                    if constexpr (sizeof(TC) == 2)
                        C[(size_t)row * ldc + col] = f2bf(acc[mi][ni][q]);
                    else
                        C[(size_t)row * ldc + col] = acc[mi][ni][q];
                }
            }
        }
    }
}

// =====================================================================
// MFMA GEMM (m97 recipe, BK=32, batch strides) — used for ymm (K=64).
// =====================================================================
template <typename TC>
__global__ __launch_bounds__(256) void gemm_mfma_bt(
    const bf16_t* __restrict__ A, int lda, size_t sAb,
    const bf16_t* __restrict__ B, int ldb, size_t sBb,
    TC* __restrict__ C, int ldc, size_t sCb,
    int M, int N, int K)
{
    __shared__ __align__(16) bf16_t As[128 * 32];
    __shared__ __align__(16) bf16_t Bs[128 * 32];
    const bf16_t* Ab = A + blockIdx.z * sAb;
    const bf16_t* Bb = B + blockIdx.z * sBb;
    TC*            Cb = C + blockIdx.z * sCb;
    const int tid = threadIdx.x;
    const int m0 = blockIdx.y * 128;
    const int n0 = blockIdx.x * 128;
    const int wid = tid >> 6;
    const int lane = tid & 63;
    const int wr = (wid >> 1) * 64;
    const int wc = (wid & 1) * 64;
    const int fr = lane & 15;
    const int fk = (lane >> 4) * 8;

    f32x4 acc[4][4];
    #pragma unroll
    for (int i = 0; i < 4; ++i)
        #pragma unroll
        for (int j = 0; j < 4; ++j) acc[i][j] = (f32x4){0.f, 0.f, 0.f, 0.f};

    const int srow = tid >> 2;
    const int scol = (tid & 3) * 8;
    const bf16_t* gA = Ab + (size_t)(m0 + srow) * lda + scol;
    const bf16_t* gB = Bb + (size_t)(n0 + srow) * ldb + scol;
    bf16_t* lA = As + tid * 8;
    bf16_t* lB = Bs + tid * 8;

    for (int k0 = 0; k0 < K; k0 += 32) {
        __builtin_amdgcn_global_load_lds(
            (const __attribute__((address_space(1))) void*)(gA + k0),
            (__attribute__((address_space(3))) void*)lA, 16, 0, 0);
        __builtin_amdgcn_global_load_lds(
            (const __attribute__((address_space(1))) void*)(gA + (size_t)64 * lda + k0),
            (__attribute__((address_space(3))) void*)(lA + 2048), 16, 0, 0);
        __builtin_amdgcn_global_load_lds(
            (const __attribute__((address_space(1))) void*)(gB + k0),
            (__attribute__((address_space(3))) void*)lB, 16, 0, 0);
        __builtin_amdgcn_global_load_lds(
            (const __attribute__((address_space(1))) void*)(gB + (size_t)64 * ldb + k0),
            (__attribute__((address_space(3))) void*)(lB + 2048), 16, 0, 0);
        __syncthreads();

        short8v a_frag[4], b_frag[4];
        #pragma unroll
        for (int m = 0; m < 4; ++m)
            a_frag[m] = *(const short8v*)&As[(wr + m * 16 + fr) * 32 + fk];
        #pragma unroll
        for (int n = 0; n < 4; ++n)
            b_frag[n] = *(const short8v*)&Bs[(wc + n * 16 + fr) * 32 + fk];
        #pragma unroll
        for (int m = 0; m < 4; ++m)
            #pragma unroll
            for (int n = 0; n < 4; ++n)
                acc[m][n] = __builtin_amdgcn_mfma_f32_16x16x32_bf16(
                    a_frag[m], b_frag[n], acc[m][n], 0, 0, 0);
        __syncthreads();
    }

    #pragma unroll
    for (int mi = 0; mi < 4; ++mi) {
        #pragma unroll
        for (int ni = 0; ni < 4; ++ni) {
            const int col = n0 + wc + ni * 16 + fr;
            if (col < N) {
                #pragma unroll
                for (int q = 0; q < 4; ++q) {
                    const int row = m0 + wr + mi * 16 + (lane >> 4) * 4 + q;
                    if constexpr (sizeof(TC) == 2)
                        Cb[(size_t)row * ldc + col] = f2bf(acc[mi][ni][q]);
                    else
                        Cb[(size_t)row * ldc + col] = acc[mi][ni][q];
                }
            }
        }
    }
}

// =====================================================================
__global__ __launch_bounds__(256) void cvt_bf16_kernel(
    const float* __restrict__ in, bf16_t* __restrict__ out, int n)
{
    const int base = (blockIdx.x * 256 + threadIdx.x) * 4;
    if (base >= n) return;
    float4 v = *(const float4*)&in[base];
    ushort4 o;
    o.x = f2bf(v.x); o.y = f2bf(v.y); o.z = f2bf(v.z); o.w = f2bf(v.w);
    *(ushort4*)&out[base] = o;
}

__global__ __launch_bounds__(256) void wpad_kernel(
    const float* __restrict__ W, bf16_t* __restrict__ Wp,
    int N, int Npad, int K)
{
    const int i = blockIdx.x * 256 + threadIdx.x;
    if (i >= Npad * K) return;
    const int r = i / K, k = i - r * K;
    Wp[i] = (r < N) ? f2bf(W[(size_t)r * K + k]) : (bf16_t)0;
}

// =====================================================================
__global__ __launch_bounds__(256) void dt_kernel(
    const bf16_t* __restrict__ zx, const float* __restrict__ dt_bias,
    float* __restrict__ dtbuf)
{
    const int idx = blockIdx.x * 256 + threadIdx.x;   // < 32768*8
    const int h = idx & 7;
    const int row = idx >> 3;
    const float v = bf2f(zx[(size_t)row * DPROJ + (DINNER + CONVD) + h]) + dt_bias[h];
    const float sp = (v > 0.f) ? (v + log1pf(expf(-v))) : log1pf(expf(v));
    dtbuf[idx] = sp;
}

// =====================================================================
// 3x3 depthwise conv + bias + SiLU, channel-vectorized x8,
// 4 vertically-stacked outputs per thread (weights amortized 4x).
// =====================================================================
__global__ __launch_bounds__(256) void conv_silu_kernel(
    const bf16_t* __restrict__ zx,
    const float* __restrict__ wA, const float* __restrict__ bA,
    const float* __restrict__ wB, const float* __restrict__ bB,
    bf16_t* __restrict__ out)
{
    const int idx = blockIdx.x * 256 + threadIdx.x;   // < 8192*80
    const int cb = idx % CBLK;
    const int pc = idx / CBLK;         // (b,h4,w) column id, < 8192
    const int c0 = cb * 8;
    const int ww = pc & (WW - 1);
    const int h4 = (pc >> 7) & 15;
    const int b  = pc >> 11;
    const int hbase = h4 * 4;
    const float* wp = (b < 2) ? wA : wB;
    const float* bp = (b < 2) ? bA : bB;

    float w[72];
    const float4* wsrc = (const float4*)(wp + c0 * 9);
    #pragma unroll
    for (int i = 0; i < 18; ++i) ((float4*)w)[i] = wsrc[i];

    float acc[4][8];
    {
        float4 bv0 = *(const float4*)(bp + c0);
        float4 bv1 = *(const float4*)(bp + c0 + 4);
        #pragma unroll
        for (int o = 0; o < 4; ++o) {
            acc[o][0] = bv0.x; acc[o][1] = bv0.y; acc[o][2] = bv0.z; acc[o][3] = bv0.w;
            acc[o][4] = bv1.x; acc[o][5] = bv1.y; acc[o][6] = bv1.z; acc[o][7] = bv1.w;
        }
    }

    const bf16_t* base = zx + (size_t)b * LSEQ * DPROJ + DINNER + c0;
    #pragma unroll
    for (int ri = 0; ri < 6; ++ri) {           // input rows hbase-1 .. hbase+4
        const int hi = hbase + ri - 1;
        const bool hok = (unsigned)hi < (unsigned)HH;
        float cur[3][8];
        #pragma unroll
        for (int kj = 0; kj < 3; ++kj) {
            const int wi = ww + kj - 1;
            if (hok && (unsigned)wi < (unsigned)WW) {
                const ushort8v v = *(const ushort8v*)(base + (size_t)(hi * WW + wi) * DPROJ);
                #pragma unroll
                for (int q = 0; q < 8; ++q) cur[kj][q] = bf2f(v[q]);
            } else {
                #pragma unroll
                for (int q = 0; q < 8; ++q) cur[kj][q] = 0.f;
            }
        }
        #pragma unroll
        for (int o = 0; o < 4; ++o) {
            const int ki = ri - o;             // tap row for output o
            if (ki >= 0 && ki < 3) {
                #pragma unroll
                for (int kj = 0; kj < 3; ++kj)
                    #pragma unroll
                    for (int q = 0; q < 8; ++q)
                        acc[o][q] += cur[kj][q] * w[q * 9 + ki * 3 + kj];
            }
        }
    }

    #pragma unroll
    for (int o = 0; o < 4; ++o) {
        const int t = b * LSEQ + (hbase + o) * WW + ww;
        ushort8v ov;
        #pragma unroll
        for (int q = 0; q < 8; ++q) {
            const float s = acc[o][q] / (1.f + expf(-acc[o][q]));   // silu
            ov[q] = f2bf(s);
        }
        *(ushort8v*)(out + (size_t)t * CONVD + c0) = ov;
    }
}

// =====================================================================
// KV partials: KVp[chunk][(b*8+h)*4096 + s*64 + p]
// =====================================================================
__global__ __launch_bounds__(128) void kv_part_kernel(
    const bf16_t* __restrict__ xconv, const float* __restrict__ dtbuf,
    const float* __restrict__ A_log, float* __restrict__ KVp)
{
    const int h = blockIdx.y, b = blockIdx.z, chunk = blockIdx.x;
    const int tid = threadIdx.x;
    const int w = tid >> 6, lane = tid & 63;
    __shared__ float lds[2 * 4352];
    float* Bt = lds + w * 4352;
    float* Xt = Bt + 2176;
    const float eA = expf(A_log[h]);
    const int s4  = (lane & 15) * 4;
    const int p16 = (lane >> 4) * 16;
    const int r    = lane & 31;
    const int part = lane >> 5;

    float acc[4][16];
    #pragma unroll
    for (int i = 0; i < 4; ++i)
        #pragma unroll
        for (int j = 0; j < 16; ++j) acc[i][j] = 0.f;

    const int l0 = b * LSEQ + chunk * 256;

    for (int t = 0; t < 8; t += 2) {
        const int row = l0 + (t + w) * 32 + r;
        const bf16_t* src = xconv + (size_t)row * CONVD + (part ? h * 64 : DINNER);
        const float scale = part ? dtbuf[row * NH + h] * eA : 1.f;
        float* dst = part ? &Xt[r * 68] : &Bt[r * 68];
        #pragma unroll
        for (int j = 0; j < 8; ++j) {
            ushort8v v = *(const ushort8v*)(src + j * 8);
            f32x4 lo = {bf2f(v[0]) * scale, bf2f(v[1]) * scale,
                        bf2f(v[2]) * scale, bf2f(v[3]) * scale};
            f32x4 hi = {bf2f(v[4]) * scale, bf2f(v[5]) * scale,
                        bf2f(v[6]) * scale, bf2f(v[7]) * scale};
            *(f32x4*)&dst[j * 8]     = lo;
            *(f32x4*)&dst[j * 8 + 4] = hi;
        }
        __syncthreads();
        #pragma unroll 4
        for (int rr = 0; rr < 32; ++rr) {
            const f32x4 bv = *(const f32x4*)&Bt[rr * 68 + s4];
            #pragma unroll
            for (int q = 0; q < 4; ++q) {
                const f32x4 xv = *(const f32x4*)&Xt[rr * 68 + p16 + q * 4];
                #pragma unroll
                for (int si = 0; si < 4; ++si)
                    #pragma unroll
                    for (int k = 0; k < 4; ++k)
                        acc[si][q * 4 + k] += bv[si] * xv[k];
            }
        }
        __syncthreads();
    }

    if (w == 0) {
        #pragma unroll
        for (int si = 0; si < 4; ++si)
            #pragma unroll
            for (int q = 0; q < 4; ++q)
                *(f32x4*)&lds[(s4 + si) * 68 + p16 + q * 4] =
                    (f32x4){acc[si][q*4], acc[si][q*4+1], acc[si][q*4+2], acc[si][q*4+3]};
    }
    __syncthreads();
    if (w == 1) {
        float* dst = KVp + ((size_t)chunk * (NB * NH) + (b * NH + h)) * 4096;
        #pragma unroll
        for (int si = 0; si < 4; ++si)
            #pragma unroll
            for (int q = 0; q < 4; ++q) {
                const f32x4 o = *(const f32x4*)&lds[(s4 + si) * 68 + p16 + q * 4];
                f32x4 v = {acc[si][q*4] + o[0], acc[si][q*4+1] + o[1],
                           acc[si][q*4+2] + o[2], acc[si][q*4+3] + o[3]};
                *(f32x4*)&dst[(s4 + si) * 64 + p16 + q * 4] = v;
            }
    }
}

// =====================================================================
// KVT[b][h*64+p][s] (bf16) = sum_chunk KVp[chunk][(b*8+h)*4096+s*64+p]
// =====================================================================
__global__ __launch_bounds__(256) void kv_reduce_T_kernel(
    const float* __restrict__ KVp, bf16_t* __restrict__ KVT)
{
    const int idx = blockIdx.x * 256 + threadIdx.x;   // < 131072
    float s = 0.f;
    #pragma unroll
    for (int c = 0; c < KVCH; ++c) s += KVp[(size_t)c * 131072 + idx];
    const int bh = idx >> 12;          // b*8+h
    const int ss = (idx >> 6) & 63;
    const int p  = idx & 63;
    KVT[((size_t)(bh * 64 + p)) * 64 + ss] = f2bf(s);
}

// =====================================================================
// LN + gate: y = Yattn + x*Dv -> LayerNorm(512) -> *g+b -> *z -> ybuf
// =====================================================================
__global__ __launch_bounds__(256) void ln_gate_kernel(
    const bf16_t* __restrict__ Yattn, const bf16_t* __restrict__ xconv,
    const bf16_t* __restrict__ zx,
    const float* __restrict__ DA, const float* __restrict__ DB,
    const float* __restrict__ ln_g, const float* __restrict__ ln_b,
    bf16_t* __restrict__ ybuf)
{
    const int w = threadIdx.x >> 6, lane = threadIdx.x & 63;
    const int c0 = lane * 8;
    const int h = lane >> 3;
    float g[8], be[8];
    *(float4*)&g[0]  = *(const float4*)&ln_g[c0];
    *(float4*)&g[4]  = *(const float4*)&ln_g[c0 + 4];
    *(float4*)&be[0] = *(const float4*)&ln_b[c0];
    *(float4*)&be[4] = *(const float4*)&ln_b[c0 + 4];
    const int row0 = (blockIdx.x * 4 + w) * 4;

    for (int i = 0; i < 4; ++i) {
        const int row = row0 + i;
        const int b = row >> 13;
        const float Dv = (b < 2) ? DA[h] : DB[h];
        ushort8v yv = *(const ushort8v*)(Yattn + (size_t)row * DINNER + c0);
        ushort8v xv = *(const ushort8v*)(xconv + (size_t)row * CONVD + c0);
        float y[8];
        float s1 = 0.f, s2 = 0.f;
        #pragma unroll
        for (int q = 0; q < 8; ++q) {
            y[q] = bf2f(yv[q]) + bf2f(xv[q]) * Dv;
            s1 += y[q]; s2 += y[q] * y[q];
        }
        #pragma unroll
        for (int off = 32; off > 0; off >>= 1) {
            s1 += __shfl_xor(s1, off, 64);
            s2 += __shfl_xor(s2, off, 64);
        }
        const float mu = s1 * (1.f / 512.f);
        const float var = s2 * (1.f / 512.f) - mu * mu;
        const float rstd = rsqrtf(var + 1e-5f);
        ushort8v zv = *(const ushort8v*)(zx + (size_t)row * DPROJ + c0);
        ushort8v o;
        #pragma unroll
        for (int q = 0; q < 8; ++q)
            o[q] = f2bf(((y[q] - mu) * rstd * g[q] + be[q]) * bf2f(zv[q]));
        *(ushort8v*)(ybuf + (size_t)row * DINNER + c0) = o;
    }
}

// =====================================================================
extern "C" void kernel_launch(void* const* d_in, const int* in_sizes, int n_in,
                              void* d_out, int out_size, void* d_ws, size_t ws_size,
                              hipStream_t stream)
{
    const float* u        = (const float*)d_in[0];
    const float* W_in     = (const float*)d_in[3];
    const float* W_st     = (const float*)d_in[4];
    const float* conv_l_w = (const float*)d_in[5];
    const float* conv_l_b = (const float*)d_in[6];
    const float* conv_r_w = (const float*)d_in[7];
    const float* conv_r_b = (const float*)d_in[8];
    const float* conv_w   = (const float*)d_in[9];
    const float* conv_b   = (const float*)d_in[10];
    const float* dt_bias  = (const float*)d_in[11];
    const float* A_log    = (const float*)d_in[12];
    const float* D_l      = (const float*)d_in[13];
    const float* D_r      = (const float*)d_in[14];
    const float* Dp       = (const float*)d_in[15];
    const float* ln_g     = (const float*)d_in[16];
    const float* ln_b     = (const float*)d_in[17];
    const float* W_out    = (const float*)d_in[18];
    float* out = (float*)d_out;

    // ---- workspace layout: ~205 MB (KVp aliases ubf; KVT bf16; Yattn bf16) ----
    char* ws = (char*)d_ws;
    const size_t ZX_B    = (size_t)MROWS * DPROJ * 2;    //  76,021,760
    const size_t XCONV_B = (size_t)MROWS * CONVD * 2;    //  41,943,040
    const size_t YBUF_B  = (size_t)MROWS * DINNER * 2;   //  33,554,432
    const size_t DT_B    = (size_t)MROWS * NH * 4;       //   1,048,576
    const size_t KVT_B   = (size_t)NB * DINNER * 64 * 2; //     262,144
    const size_t UBF_B   = (size_t)MROWS * DMODEL * 2;   //  16,777,216 (== KVCH*131072*4)
    const size_t WIN_B   = (size_t)1280 * DMODEL * 2;
    const size_t WST_B   = (size_t)1280 * DINNER * 2;
    const size_t WOUT_B  = (size_t)256 * DINNER * 2;
    bf16_t* zx    = (bf16_t*)(ws);
    bf16_t* xconv = (bf16_t*)(ws + ZX_B);
    bf16_t* ybuf  = (bf16_t*)(ws + ZX_B + XCONV_B);
    float*  dtbuf = (float*) (ws + ZX_B + XCONV_B + YBUF_B);
    bf16_t* KVT   = (bf16_t*)(ws + ZX_B + XCONV_B + YBUF_B + DT_B);
    bf16_t* ubf   = (bf16_t*)(ws + ZX_B + XCONV_B + YBUF_B + DT_B + KVT_B);
    float*  KVp   = (float*) (ws + ZX_B + XCONV_B + YBUF_B + DT_B + KVT_B);  // alias (ubf dead after gemm1)
    bf16_t* WinP  = (bf16_t*)(ws + ZX_B + XCONV_B + YBUF_B + DT_B + KVT_B + UBF_B);
    bf16_t* WstP  = (bf16_t*)(ws + ZX_B + XCONV_B + YBUF_B + DT_B + KVT_B + UBF_B + WIN_B);
    bf16_t* WoutP = (bf16_t*)(ws + ZX_B + XCONV_B + YBUF_B + DT_B + KVT_B + UBF_B + WIN_B + WST_B);
    bf16_t* Yattn = (bf16_t*)(ws + ZX_B + XCONV_B + YBUF_B + DT_B + KVT_B + UBF_B + WIN_B + WST_B + WOUT_B);

    const dim3 gemmGridP(10, MROWS / 128);        // Npad=1280, 2560 blocks (%8==0)
    const dim3 gemmGridO(2,  MROWS / 128);        // N=256, 512 blocks (%8==0)
    const dim3 ymmGrid(4, LSEQ / 128, NB);        // N=512, per-batch
    const dim3 kvGrid(KVCH, NH, NB);
    const int convGrid = (MROWS / 4) * CBLK / 256; // 2560
    const int lnGrid = MROWS / 16;                 // 2048

    // ---- one-time conversions ----
    cvt_bf16_kernel<<<(MROWS * DMODEL / 4 + 255) / 256, 256, 0, stream>>>(u, ubf, MROWS * DMODEL);
    wpad_kernel<<<(1280 * DMODEL + 255) / 256, 256, 0, stream>>>(W_in, WinP, DPROJ, 1280, DMODEL);
    wpad_kernel<<<(1280 * DINNER + 255) / 256, 256, 0, stream>>>(W_st, WstP, DPROJ, 1280, DINNER);
    wpad_kernel<<<(256 * DINNER + 255) / 256, 256, 0, stream>>>(W_out, WoutP, DMODEL, 256, DINNER);

    // ---------------- pass 1 ----------------
    gemm_mfma_bk64<bf16_t><<<gemmGridP, 256, 0, stream>>>(
        ubf, DMODEL, WinP, DMODEL, zx, DPROJ, MROWS, DPROJ, DMODEL);
    dt_kernel<<<(MROWS * NH) / 256, 256, 0, stream>>>(zx, dt_bias, dtbuf);
    conv_silu_kernel<<<convGrid, 256, 0, stream>>>(
        zx, conv_l_w, conv_l_b, conv_r_w, conv_r_b, xconv);
    kv_part_kernel<<<kvGrid, 128, 0, stream>>>(xconv, dtbuf, A_log, KVp);
    kv_reduce_T_kernel<<<131072 / 256, 256, 0, stream>>>(KVp, KVT);
    gemm_mfma_bt<bf16_t><<<ymmGrid, 256, 0, stream>>>(
        xconv + DINNER + DSTATE, CONVD, (size_t)LSEQ * CONVD,
        KVT, 64, (size_t)DINNER * 64,
        Yattn, DINNER, (size_t)LSEQ * DINNER, LSEQ, DINNER, 64);
    ln_gate_kernel<<<lnGrid, 256, 0, stream>>>(
        Yattn, xconv, zx, D_l, D_r, ln_g, ln_b, ybuf);

    // ---------------- pass 2 ----------------
    gemm_mfma_bk64<bf16_t><<<gemmGridP, 256, 0, stream>>>(
        ybuf, DINNER, WstP, DINNER, zx, DPROJ, MROWS, DPROJ, DINNER);
    dt_kernel<<<(MROWS * NH) / 256, 256, 0, stream>>>(zx, dt_bias, dtbuf);
    conv_silu_kernel<<<convGrid, 256, 0, stream>>>(
        zx, conv_w, conv_b, conv_w, conv_b, xconv);
    kv_part_kernel<<<kvGrid, 128, 0, stream>>>(xconv, dtbuf, A_log, KVp);
    kv_reduce_T_kernel<<<131072 / 256, 256, 0, stream>>>(KVp, KVT);
    gemm_mfma_bt<bf16_t><<<ymmGrid, 256, 0, stream>>>(
        xconv + DINNER + DSTATE, CONVD, (size_t)LSEQ * CONVD,
        KVT, 64, (size_t)DINNER * 64,
        Yattn, DINNER, (size_t)LSEQ * DINNER, LSEQ, DINNER, 64);
    ln_gate_kernel<<<lnGrid, 256, 0, stream>>>(
        Yattn, xconv, zx, Dp, Dp, ln_g, ln_b, ybuf);

    // ---------------- output projection ----------------
    gemm_mfma_bk64<float><<<gemmGridO, 256, 0, stream>>>(
        ybuf, DINNER, WoutP, DINNER, out, DMODEL, MROWS, DMODEL, DINNER);
}